// Round 3
// baseline (7390.190 us; speedup 1.0000x reference)
//
#include <hip/hip_runtime.h>
#include <hip/hip_bf16.h>

typedef __hip_bfloat16 bf16;

#define FDIM 64
#define HDIM 128

__device__ __forceinline__ float b2f(bf16 v) { return __bfloat162float(v); }
__device__ __forceinline__ float bits2f(unsigned short u) {
    return __uint_as_float(((unsigned int)u) << 16);
}

// ---------------- runtime dtype detection (device-side, graph-safe) ----------------
// flags[0]=1 if float inputs are f32 (else bf16); flags[1]=1 if edge is int64;
// flags[2]=1 if batch is int64.
__global__ void k_detect(const unsigned short* __restrict__ w1u,
                         const int* __restrict__ edge,
                         const int* __restrict__ batch,
                         int* __restrict__ flags) {
    if (threadIdx.x != 0 || blockIdx.x != 0) return;
    int wild = 0;
    for (int i = 0; i < 256; i += 2) {          // even ushorts: low halves if f32
        int e = (w1u[i] >> 7) & 0xFF;           // bf16-view exponent
        if (e == 0 || e >= 137) wild++;         // zero/denorm or |v|>~1024/Inf/NaN
    }
    flags[0] = (wild > 16) ? 1 : 0;
    int z = 0;
    for (int i = 1; i < 256; i += 2) z += (edge[i] == 0);   // odd words: i64 high halves
    flags[1] = (z > 64) ? 1 : 0;
    z = 0;
    for (int i = 1025; i < 1281; i += 2) z += (batch[i] == 0);
    flags[2] = (z > 64) ? 1 : 0;
}

// convert float tensor (f32 or bf16 per flag) to canonical bf16
__global__ void k_convert(const void* __restrict__ src, bf16* __restrict__ dst,
                          int n, const int* __restrict__ flags) {
    int i = blockIdx.x * 256 + threadIdx.x;
    if (i >= n) return;
    if (flags[0]) dst[i] = __float2bfloat16(((const float*)src)[i]);
    else          dst[i] = ((const bf16*)src)[i];
}

__device__ __forceinline__ int edge_word(const int* e, int logical_idx, int is64) {
    return is64 ? e[2 * logical_idx] : e[logical_idx];
}

// ---------------- degree ----------------
__global__ void k_init_deg(float* __restrict__ deg, int N) {
    int i = blockIdx.x * blockDim.x + threadIdx.x;
    if (i < N) deg[i] = 1.0f;  // +1 self loop
}

__global__ void k_deg(const int* __restrict__ edge, float* __restrict__ deg, int E,
                      const int* __restrict__ flags) {
    int i = blockIdx.x * blockDim.x + threadIdx.x;
    if (i >= E) return;
    int d = edge_word(edge, E + i, flags[1]);
    atomicAdd(&deg[d], 1.0f);
}

__global__ void k_dinv(float* __restrict__ dinv, int N) {
    int i = blockIdx.x * blockDim.x + threadIdx.x;
    if (i < N) dinv[i] = rsqrtf(dinv[i]);
}

// ---------------- GEMM1: h1[N,128] = x[N,64] @ W1[64,128], out bf16 ----------------
__global__ __launch_bounds__(256) void k_gemm1(const void* __restrict__ x,
                                               const bf16* __restrict__ W1,
                                               bf16* __restrict__ h1, int N,
                                               const int* __restrict__ flags) {
    __shared__ float Wl[FDIM * HDIM];   // 32 KB
    __shared__ float Xl[8 * FDIM];      // 2 KB
    int tid = threadIdx.x;
    for (int i = tid; i < FDIM * HDIM; i += 256) Wl[i] = b2f(W1[i]);
    int base = blockIdx.x * 8;
    if (flags[0]) {
        const float* xf = (const float*)x;
        for (int i = tid; i < 8 * FDIM; i += 256) {
            int r = i >> 6, k = i & 63;
            Xl[i] = xf[(size_t)(base + r) * FDIM + k];
        }
    } else {
        const bf16* xb = (const bf16*)x;
        for (int i = tid; i < 8 * FDIM; i += 256) {
            int r = i >> 6, k = i & 63;
            Xl[i] = b2f(xb[(size_t)(base + r) * FDIM + k]);
        }
    }
    __syncthreads();
    int col = tid & 127, r0 = tid >> 7;
    float acc[4] = {0.f, 0.f, 0.f, 0.f};
    for (int k = 0; k < FDIM; k++) {
        float wv = Wl[k * HDIM + col];
#pragma unroll
        for (int j = 0; j < 4; j++) acc[j] += Xl[(r0 * 4 + j) * FDIM + k] * wv;
    }
#pragma unroll
    for (int j = 0; j < 4; j++)
        h1[(size_t)(base + r0 * 4 + j) * HDIM + col] = __float2bfloat16(acc[j]);
}

// ---------------- GEMM2: h2[N,128](bf16) = act[N,128](f32) @ W2[128,128] ----------------
__global__ __launch_bounds__(256) void k_gemm2(const float* __restrict__ xin,
                                               const bf16* __restrict__ W2,
                                               bf16* __restrict__ outp, int N) {
    __shared__ bf16 Wl[HDIM * HDIM];    // 32 KB
    __shared__ float Xl[8 * HDIM];      // 4 KB
    int tid = threadIdx.x;
    for (int i = tid; i < HDIM * HDIM; i += 256) Wl[i] = W2[i];
    int base = blockIdx.x * 8;
    for (int i = tid; i < 8 * HDIM; i += 256) {
        int r = i >> 7, k = i & 127;
        Xl[i] = xin[(size_t)(base + r) * HDIM + k];
    }
    __syncthreads();
    int col = tid & 127, r0 = tid >> 7;
    float acc[4] = {0.f, 0.f, 0.f, 0.f};
    for (int k = 0; k < HDIM; k++) {
        float wv = b2f(Wl[k * HDIM + col]);
#pragma unroll
        for (int j = 0; j < 4; j++) acc[j] += Xl[(r0 * 4 + j) * HDIM + k] * wv;
    }
#pragma unroll
    for (int j = 0; j < 4; j++)
        outp[(size_t)(base + r0 * 4 + j) * HDIM + col] = __float2bfloat16(acc[j]);
}

// ---------------- scatter: agg[dst] += h[src]*norm (h bf16) ----------------
__global__ __launch_bounds__(256) void k_scatter(const bf16* __restrict__ h,
                                                 const int* __restrict__ edge,
                                                 const float* __restrict__ dinv,
                                                 float* __restrict__ agg, int E,
                                                 const int* __restrict__ flags) {
    int gid = blockIdx.x * 256 + threadIdx.x;
    int e = gid >> 4;
    if (e >= E) return;
    int is64 = flags[1];
    int f8 = (gid & 15) << 3;
    int s = edge_word(edge, e, is64);
    int d = edge_word(edge, E + e, is64);
    float norm = dinv[s] * dinv[d];
    union { float4 f; unsigned short us[8]; } u;
    u.f = *reinterpret_cast<const float4*>(h + (size_t)s * HDIM + f8);
    float* bp = agg + (size_t)d * HDIM + f8;
#pragma unroll
    for (int j = 0; j < 8; j++) atomicAdd(bp + j, bits2f(u.us[j]) * norm);
}

// ---------------- epilogue: agg = relu(agg + h*deg^-1 + b) ----------------
__global__ __launch_bounds__(256) void k_epilogue(const bf16* __restrict__ hself,
                                                  float* __restrict__ agg,
                                                  const bf16* __restrict__ bias,
                                                  const float* __restrict__ dinv, int N) {
    int i4 = blockIdx.x * blockDim.x + threadIdx.x;
    if (i4 >= N * (HDIM / 4)) return;
    size_t i = (size_t)i4 * 4;
    int row = (int)(i >> 7);
    int col = (int)(i & 127);
    float id = dinv[row];
    id = id * id;
    float4 a = *reinterpret_cast<const float4*>(agg + i);
    union { unsigned long long q; unsigned short us[4]; } hu;
    hu.q = *reinterpret_cast<const unsigned long long*>(hself + i);
    float b0 = b2f(bias[col + 0]), b1 = b2f(bias[col + 1]);
    float b2v = b2f(bias[col + 2]), b3 = b2f(bias[col + 3]);
    a.x = fmaxf(a.x + bits2f(hu.us[0]) * id + b0, 0.f);
    a.y = fmaxf(a.y + bits2f(hu.us[1]) * id + b1, 0.f);
    a.z = fmaxf(a.z + bits2f(hu.us[2]) * id + b2v, 0.f);
    a.w = fmaxf(a.w + bits2f(hu.us[3]) * id + b3, 0.f);
    *reinterpret_cast<float4*>(agg + i) = a;
}

// ---------------- pool + fc + softmax ----------------
__global__ __launch_bounds__(128) void k_pool(const float* __restrict__ hact,
                                              const int* __restrict__ batch,
                                              const bf16* __restrict__ Wfc,
                                              const bf16* __restrict__ bfc,
                                              void* __restrict__ out, int N, int G,
                                              const int* __restrict__ flags) {
    int g = blockIdx.x;
    int t = threadIdx.x;
    int is64 = flags[2];
    int lo = 0, hi = N;
    while (lo < hi) {
        int mid = (lo + hi) >> 1;
        int bm = is64 ? batch[2 * mid] : batch[mid];
        if (bm < g) lo = mid + 1; else hi = mid;
    }
    int start = lo;
    hi = N;
    while (lo < hi) {
        int mid = (lo + hi) >> 1;
        int bm = is64 ? batch[2 * mid] : batch[mid];
        if (bm < g + 1) lo = mid + 1; else hi = mid;
    }
    int end = lo;

    float sum = 0.f;
    for (int r = start; r < end; r++) sum += hact[(size_t)r * HDIM + t];
    float cnt = (float)(end - start);
    float mean = sum / fmaxf(cnt, 1.0f);

    __shared__ float l0[128];
    __shared__ float l1[128];
    l0[t] = mean * b2f(Wfc[t * 2 + 0]);
    l1[t] = mean * b2f(Wfc[t * 2 + 1]);
    __syncthreads();
    for (int sft = 64; sft > 0; sft >>= 1) {
        if (t < sft) { l0[t] += l0[t + sft]; l1[t] += l1[t + sft]; }
        __syncthreads();
    }
    if (t == 0) {
        float z0 = l0[0] + b2f(bfc[0]);
        float z1 = l1[0] + b2f(bfc[1]);
        float m = fmaxf(z0, z1);
        float e0 = expf(z0 - m), e1 = expf(z1 - m);
        float s = e0 + e1;
        float p0 = e0 / s, p1 = e1 / s;
        if (flags[0]) {
            ((float*)out)[g * 2 + 0] = p0;
            ((float*)out)[g * 2 + 1] = p1;
        } else {
            ((bf16*)out)[g * 2 + 0] = __float2bfloat16(p0);
            ((bf16*)out)[g * 2 + 1] = __float2bfloat16(p1);
        }
    }
}

extern "C" void kernel_launch(void* const* d_in, const int* in_sizes, int n_in,
                              void* d_out, int out_size, void* d_ws, size_t ws_size,
                              hipStream_t stream) {
    const void* x    = d_in[0];
    const int*  edge = (const int*)d_in[1];
    const int*  batch= (const int*)d_in[2];
    const void* W1  = d_in[4];
    const void* b1  = d_in[5];
    const void* W2  = d_in[6];
    const void* b2  = d_in[7];
    const void* Wfc = d_in[8];
    const void* bfc = d_in[9];

    int N = in_sizes[0] / FDIM;   // 100000
    int E = in_sizes[1] / 2;      // 1000000
    int G = out_size / 2;         // 512

    // workspace layout (~77.3 MB):
    int*   flags = (int*)d_ws;                              // 64 B reserved
    float* dinv  = (float*)((char*)d_ws + 64);              // N f32
    float* Abuf  = dinv + N;                                // N*128 f32
    bf16*  Hbuf  = (bf16*)(Abuf + (size_t)N * HDIM);        // N*128 bf16
    bf16*  W1c   = Hbuf + (size_t)N * HDIM;                 // 8192
    bf16*  b1c   = W1c + FDIM * HDIM;                       // 128
    bf16*  W2c   = b1c + HDIM;                              // 16384
    bf16*  b2c   = W2c + HDIM * HDIM;                       // 128
    bf16*  Wfcc  = b2c + HDIM;                              // 256
    bf16*  bfcc  = Wfcc + 256;                              // 2

    k_detect<<<1, 64, 0, stream>>>((const unsigned short*)W1, edge, batch, flags);
    k_convert<<<(FDIM * HDIM + 255) / 256, 256, 0, stream>>>(W1, W1c, FDIM * HDIM, flags);
    k_convert<<<1, 256, 0, stream>>>(b1, b1c, HDIM, flags);
    k_convert<<<(HDIM * HDIM + 255) / 256, 256, 0, stream>>>(W2, W2c, HDIM * HDIM, flags);
    k_convert<<<1, 256, 0, stream>>>(b2, b2c, HDIM, flags);
    k_convert<<<1, 256, 0, stream>>>(Wfc, Wfcc, 256, flags);
    k_convert<<<1, 256, 0, stream>>>(bfc, bfcc, 2, flags);

    // degrees
    k_init_deg<<<(N + 255) / 256, 256, 0, stream>>>(dinv, N);
    k_deg<<<(E + 255) / 256, 256, 0, stream>>>(edge, dinv, E, flags);
    k_dinv<<<(N + 255) / 256, 256, 0, stream>>>(dinv, N);

    // layer 1
    k_gemm1<<<N / 8, 256, 0, stream>>>(x, W1c, Hbuf, N, flags);
    hipMemsetAsync(Abuf, 0, (size_t)N * HDIM * sizeof(float), stream);
    k_scatter<<<(int)(((long long)E * 16 + 255) / 256), 256, 0, stream>>>(Hbuf, edge, dinv, Abuf, E, flags);
    k_epilogue<<<(N * (HDIM / 4) + 255) / 256, 256, 0, stream>>>(Hbuf, Abuf, b1c, dinv, N);

    // layer 2
    k_gemm2<<<N / 8, 256, 0, stream>>>(Abuf, W2c, Hbuf, N);
    hipMemsetAsync(Abuf, 0, (size_t)N * HDIM * sizeof(float), stream);
    k_scatter<<<(int)(((long long)E * 16 + 255) / 256), 256, 0, stream>>>(Hbuf, edge, dinv, Abuf, E, flags);
    k_epilogue<<<(N * (HDIM / 4) + 255) / 256, 256, 0, stream>>>(Hbuf, Abuf, b2c, dinv, N);

    // pool + fc + softmax
    k_pool<<<G, 128, 0, stream>>>(Abuf, batch, Wfcc, bfcc, d_out, N, G, flags);
}

// Round 4
// 598.080 us; speedup vs baseline: 12.3565x; 12.3565x over previous
//
#include <hip/hip_runtime.h>
#include <hip/hip_bf16.h>

typedef __hip_bfloat16 bf16;

#define FDIM 64
#define HDIM 128
#define SCHUNK 512

__device__ __forceinline__ float b2f(bf16 v) { return __bfloat162float(v); }
__device__ __forceinline__ float bits2f(unsigned int u) {
    return __uint_as_float(u << 16);
}
__device__ __forceinline__ unsigned short f2bits(float f) {
    bf16 b = __float2bfloat16(f);
    return *reinterpret_cast<unsigned short*>(&b);
}

// ---------------- runtime dtype detection ----------------
__global__ void k_detect(const unsigned short* __restrict__ w1u,
                         const int* __restrict__ edge,
                         const int* __restrict__ batch,
                         int* __restrict__ flags) {
    if (threadIdx.x != 0 || blockIdx.x != 0) return;
    int wild = 0;
    for (int i = 0; i < 256; i += 2) {
        int e = (w1u[i] >> 7) & 0xFF;
        if (e == 0 || e >= 137) wild++;
    }
    flags[0] = (wild > 16) ? 1 : 0;
    int z = 0;
    for (int i = 1; i < 256; i += 2) z += (edge[i] == 0);
    flags[1] = (z > 64) ? 1 : 0;
    z = 0;
    for (int i = 1025; i < 1281; i += 2) z += (batch[i] == 0);
    flags[2] = (z > 64) ? 1 : 0;
}

__global__ void k_convert(const void* __restrict__ src, bf16* __restrict__ dst,
                          int n, const int* __restrict__ flags) {
    int i = blockIdx.x * 256 + threadIdx.x;
    if (i >= n) return;
    if (flags[0]) dst[i] = __float2bfloat16(((const float*)src)[i]);
    else          dst[i] = ((const bf16*)src)[i];
}

__device__ __forceinline__ int edge_word(const int* e, long long logical_idx, int is64) {
    return is64 ? e[2 * logical_idx] : e[logical_idx];
}

// ---------------- CSR build ----------------
__global__ void k_count(const int* __restrict__ edge, int* __restrict__ count, int E,
                        const int* __restrict__ flags) {
    int i = blockIdx.x * blockDim.x + threadIdx.x;
    if (i >= E) return;
    int d = edge_word(edge, (long long)E + i, flags[1]);
    atomicAdd(&count[d], 1);
}

__global__ void k_dinv(const int* __restrict__ count, float* __restrict__ dinv, int N) {
    int i = blockIdx.x * blockDim.x + threadIdx.x;
    if (i < N) dinv[i] = rsqrtf((float)count[i] + 1.0f);
}

// per-chunk sums: 256 threads handle SCHUNK=512 counts
__global__ __launch_bounds__(256) void k_scan_partial(const int* __restrict__ count,
                                                      int* __restrict__ parts, int N) {
    __shared__ int red[256];
    int base = blockIdx.x * SCHUNK;
    int t = threadIdx.x;
    int i0 = base + 2 * t, i1 = base + 2 * t + 1;
    int v = 0;
    if (i0 < N) v += count[i0];
    if (i1 < N) v += count[i1];
    red[t] = v;
    __syncthreads();
    for (int s = 128; s > 0; s >>= 1) {
        if (t < s) red[t] += red[t + s];
        __syncthreads();
    }
    if (t == 0) parts[blockIdx.x] = red[0];
}

// exclusive scan of up to 256 partials, single block
__global__ __launch_bounds__(256) void k_scan_parts(const int* __restrict__ parts,
                                                    int* __restrict__ partsx, int NP) {
    __shared__ int a[256], b[256];
    int t = threadIdx.x;
    int own = (t < NP) ? parts[t] : 0;
    a[t] = own;
    __syncthreads();
    int* cur = a; int* nxt = b;
    for (int off = 1; off < 256; off <<= 1) {
        int v = cur[t];
        if (t >= off) v += cur[t - off];
        nxt[t] = v;
        __syncthreads();
        int* tmp = cur; cur = nxt; nxt = tmp;
    }
    if (t < NP) partsx[t] = cur[t] - own;   // exclusive
}

// per-chunk exclusive scan + chunk offset -> rowptr
__global__ __launch_bounds__(512) void k_scan_final(const int* __restrict__ count,
                                                    const int* __restrict__ partsx,
                                                    int* __restrict__ rowptr, int N) {
    __shared__ int a[512], b[512];
    int t = threadIdx.x;
    int idx = blockIdx.x * SCHUNK + t;
    int own = (idx < N) ? count[idx] : 0;
    a[t] = own;
    __syncthreads();
    int* cur = a; int* nxt = b;
    for (int off = 1; off < 512; off <<= 1) {
        int v = cur[t];
        if (t >= off) v += cur[t - off];
        nxt[t] = v;
        __syncthreads();
        int* tmp = cur; cur = nxt; nxt = tmp;
    }
    if (idx < N) rowptr[idx] = cur[t] - own + partsx[blockIdx.x];
}

__global__ void k_fill(const int* __restrict__ edge, const int* __restrict__ rowptr,
                       int* __restrict__ cursor, int* __restrict__ srclist, int E,
                       const int* __restrict__ flags) {
    int i = blockIdx.x * blockDim.x + threadIdx.x;
    if (i >= E) return;
    int is64 = flags[1];
    int s = edge_word(edge, i, is64);
    int d = edge_word(edge, (long long)E + i, is64);
    int pos = rowptr[d] + atomicAdd(&cursor[d], 1);
    srclist[pos] = s;
}

// ---------------- GEMM1: h1[N,128](bf16) = x[N,64](f32|bf16) @ W1[64,128] ----------------
__global__ __launch_bounds__(256) void k_gemm1(const void* __restrict__ x,
                                               const bf16* __restrict__ W1,
                                               bf16* __restrict__ h1, int N,
                                               const int* __restrict__ flags) {
    __shared__ float Wl[FDIM * HDIM];
    __shared__ float Xl[8 * FDIM];
    int tid = threadIdx.x;
    for (int i = tid; i < FDIM * HDIM; i += 256) Wl[i] = b2f(W1[i]);
    int base = blockIdx.x * 8;
    if (flags[0]) {
        const float* xf = (const float*)x;
        for (int i = tid; i < 8 * FDIM; i += 256) {
            int r = i >> 6, k = i & 63;
            Xl[i] = xf[(size_t)(base + r) * FDIM + k];
        }
    } else {
        const bf16* xb = (const bf16*)x;
        for (int i = tid; i < 8 * FDIM; i += 256) {
            int r = i >> 6, k = i & 63;
            Xl[i] = b2f(xb[(size_t)(base + r) * FDIM + k]);
        }
    }
    __syncthreads();
    int col = tid & 127, r0 = tid >> 7;
    float acc[4] = {0.f, 0.f, 0.f, 0.f};
    for (int k = 0; k < FDIM; k++) {
        float wv = Wl[k * HDIM + col];
#pragma unroll
        for (int j = 0; j < 4; j++) acc[j] += Xl[(r0 * 4 + j) * FDIM + k] * wv;
    }
#pragma unroll
    for (int j = 0; j < 4; j++)
        h1[(size_t)(base + r0 * 4 + j) * HDIM + col] = __float2bfloat16(acc[j]);
}

// ---------------- GEMM2: h2[N,128](bf16) = act[N,128](bf16) @ W2[128,128] ----------------
__global__ __launch_bounds__(256) void k_gemm2(const bf16* __restrict__ xin,
                                               const bf16* __restrict__ W2,
                                               bf16* __restrict__ outp, int N) {
    __shared__ bf16 Wl[HDIM * HDIM];
    __shared__ float Xl[8 * HDIM];
    int tid = threadIdx.x;
    for (int i = tid; i < HDIM * HDIM; i += 256) Wl[i] = W2[i];
    int base = blockIdx.x * 8;
    for (int i = tid; i < 8 * HDIM; i += 256) {
        int r = i >> 7, k = i & 127;
        Xl[i] = b2f(xin[(size_t)(base + r) * HDIM + k]);
    }
    __syncthreads();
    int col = tid & 127, r0 = tid >> 7;
    float acc[4] = {0.f, 0.f, 0.f, 0.f};
    for (int k = 0; k < HDIM; k++) {
        float wv = b2f(Wl[k * HDIM + col]);
#pragma unroll
        for (int j = 0; j < 4; j++) acc[j] += Xl[(r0 * 4 + j) * HDIM + k] * wv;
    }
#pragma unroll
    for (int j = 0; j < 4; j++)
        outp[(size_t)(base + r0 * 4 + j) * HDIM + col] = __float2bfloat16(acc[j]);
}

// ---------------- aggregate: out[i] = relu(dinv[i]*Σ h[s]*dinv[s] + h[i]*dinv²[i] + b) ----------------
// one wave per node; lane holds features {2l, 2l+1} (4B bf16x2 loads).
__global__ __launch_bounds__(256) void k_aggregate(const bf16* __restrict__ h,
                                                   const int* __restrict__ srclist,
                                                   const int* __restrict__ rowptr,
                                                   const int* __restrict__ count,
                                                   const float* __restrict__ dinv,
                                                   const bf16* __restrict__ bias,
                                                   bf16* __restrict__ outb, int N) {
    int wid = threadIdx.x >> 6;
    int lane = threadIdx.x & 63;
    int i = blockIdx.x * 4 + wid;
    if (i >= N) return;
    int start = rowptr[i];
    int cnt = count[i];
    float di = dinv[i];
    const unsigned int* hrow = (const unsigned int*)h;  // 1 uint = 2 bf16
    float a0 = 0.f, a1 = 0.f;
    int j = 0;
    for (; j + 1 < cnt; j += 2) {
        int s0 = srclist[start + j];
        int s1 = srclist[start + j + 1];
        unsigned int v0 = hrow[(size_t)s0 * 64 + lane];
        unsigned int v1 = hrow[(size_t)s1 * 64 + lane];
        float d0 = dinv[s0], d1 = dinv[s1];
        a0 += bits2f(v0 & 0xFFFFu) * d0;
        a1 += bits2f(v0 >> 16) * d0;
        a0 += bits2f(v1 & 0xFFFFu) * d1;
        a1 += bits2f(v1 >> 16) * d1;
    }
    if (j < cnt) {
        int s0 = srclist[start + j];
        unsigned int v0 = hrow[(size_t)s0 * 64 + lane];
        float d0 = dinv[s0];
        a0 += bits2f(v0 & 0xFFFFu) * d0;
        a1 += bits2f(v0 >> 16) * d0;
    }
    unsigned int vs = hrow[(size_t)i * 64 + lane];
    float self = di * di;
    float b0 = b2f(bias[2 * lane]);
    float b1 = b2f(bias[2 * lane + 1]);
    float r0 = fmaxf(di * a0 + bits2f(vs & 0xFFFFu) * self + b0, 0.f);
    float r1 = fmaxf(di * a1 + bits2f(vs >> 16) * self + b1, 0.f);
    unsigned int packed = ((unsigned int)f2bits(r1) << 16) | f2bits(r0);
    ((unsigned int*)outb)[(size_t)i * 64 + lane] = packed;
}

// ---------------- pool + fc + softmax ----------------
__global__ __launch_bounds__(128) void k_pool(const bf16* __restrict__ hact,
                                              const int* __restrict__ batch,
                                              const bf16* __restrict__ Wfc,
                                              const bf16* __restrict__ bfc,
                                              void* __restrict__ out, int N, int G,
                                              const int* __restrict__ flags) {
    int g = blockIdx.x;
    int t = threadIdx.x;
    int is64 = flags[2];
    int lo = 0, hi = N;
    while (lo < hi) {
        int mid = (lo + hi) >> 1;
        int bm = is64 ? batch[2 * mid] : batch[mid];
        if (bm < g) lo = mid + 1; else hi = mid;
    }
    int start = lo;
    hi = N;
    while (lo < hi) {
        int mid = (lo + hi) >> 1;
        int bm = is64 ? batch[2 * mid] : batch[mid];
        if (bm < g + 1) lo = mid + 1; else hi = mid;
    }
    int end = lo;

    float sum = 0.f;
    for (int r = start; r < end; r++) sum += b2f(hact[(size_t)r * HDIM + t]);
    float cnt = (float)(end - start);
    float mean = sum / fmaxf(cnt, 1.0f);

    __shared__ float l0[128];
    __shared__ float l1[128];
    l0[t] = mean * b2f(Wfc[t * 2 + 0]);
    l1[t] = mean * b2f(Wfc[t * 2 + 1]);
    __syncthreads();
    for (int sft = 64; sft > 0; sft >>= 1) {
        if (t < sft) { l0[t] += l0[t + sft]; l1[t] += l1[t + sft]; }
        __syncthreads();
    }
    if (t == 0) {
        float z0 = l0[0] + b2f(bfc[0]);
        float z1 = l1[0] + b2f(bfc[1]);
        float m = fmaxf(z0, z1);
        float e0 = expf(z0 - m), e1 = expf(z1 - m);
        float s = e0 + e1;
        float p0 = e0 / s, p1 = e1 / s;
        if (flags[0]) {
            ((float*)out)[g * 2 + 0] = p0;
            ((float*)out)[g * 2 + 1] = p1;
        } else {
            ((bf16*)out)[g * 2 + 0] = __float2bfloat16(p0);
            ((bf16*)out)[g * 2 + 1] = __float2bfloat16(p1);
        }
    }
}

extern "C" void kernel_launch(void* const* d_in, const int* in_sizes, int n_in,
                              void* d_out, int out_size, void* d_ws, size_t ws_size,
                              hipStream_t stream) {
    const void* x    = d_in[0];
    const int*  edge = (const int*)d_in[1];
    const int*  batch= (const int*)d_in[2];
    const void* W1  = d_in[4];
    const void* b1  = d_in[5];
    const void* W2  = d_in[6];
    const void* b2  = d_in[7];
    const void* Wfc = d_in[8];
    const void* bfc = d_in[9];

    int N = in_sizes[0] / FDIM;   // 100000
    int E = in_sizes[1] / 2;      // 1000000
    int G = out_size / 2;         // 512
    int NP = (N + SCHUNK - 1) / SCHUNK;  // 196 (must be <=256)

    // workspace layout (~57 MB, all 4B-aligned):
    int*   flags  = (int*)d_ws;                          // 64 B
    float* dinv   = (float*)((char*)d_ws + 64);          // N
    int*   count  = (int*)(dinv + N);                    // N
    int*   rowptr = count + N;                           // N
    int*   cursor = rowptr + N;                          // N
    int*   parts  = cursor + N;                          // 256
    int*   partsx = parts + 256;                         // 256
    int*   srclist= partsx + 256;                        // E
    bf16*  Hbuf   = (bf16*)(srclist + E);                // N*128
    bf16*  Bbuf   = Hbuf + (size_t)N * HDIM;             // N*128
    bf16*  W1c    = Bbuf + (size_t)N * HDIM;             // 8192
    bf16*  b1c    = W1c + FDIM * HDIM;                   // 128
    bf16*  W2c    = b1c + HDIM;                          // 16384
    bf16*  b2c    = W2c + HDIM * HDIM;                   // 128
    bf16*  Wfcc   = b2c + HDIM;                          // 256
    bf16*  bfcc   = Wfcc + 256;                          // 2

    k_detect<<<1, 64, 0, stream>>>((const unsigned short*)W1, edge, batch, flags);
    k_convert<<<(FDIM * HDIM + 255) / 256, 256, 0, stream>>>(W1, W1c, FDIM * HDIM, flags);
    k_convert<<<1, 256, 0, stream>>>(b1, b1c, HDIM, flags);
    k_convert<<<(HDIM * HDIM + 255) / 256, 256, 0, stream>>>(W2, W2c, HDIM * HDIM, flags);
    k_convert<<<1, 256, 0, stream>>>(b2, b2c, HDIM, flags);
    k_convert<<<1, 256, 0, stream>>>(Wfc, Wfcc, 256, flags);
    k_convert<<<1, 256, 0, stream>>>(bfc, bfcc, 2, flags);

    // CSR build (shared by both layers)
    hipMemsetAsync(count, 0, (size_t)N * sizeof(int), stream);
    hipMemsetAsync(cursor, 0, (size_t)N * sizeof(int), stream);
    k_count<<<(E + 255) / 256, 256, 0, stream>>>(edge, count, E, flags);
    k_dinv<<<(N + 255) / 256, 256, 0, stream>>>(count, dinv, N);
    k_scan_partial<<<NP, 256, 0, stream>>>(count, parts, N);
    k_scan_parts<<<1, 256, 0, stream>>>(parts, partsx, NP);
    k_scan_final<<<NP, 512, 0, stream>>>(count, partsx, rowptr, N);
    k_fill<<<(E + 255) / 256, 256, 0, stream>>>(edge, rowptr, cursor, srclist, E, flags);

    // layer 1
    k_gemm1<<<(N + 7) / 8, 256, 0, stream>>>(x, W1c, Hbuf, N, flags);
    k_aggregate<<<(N + 3) / 4, 256, 0, stream>>>(Hbuf, srclist, rowptr, count, dinv, b1c, Bbuf, N);

    // layer 2
    k_gemm2<<<(N + 7) / 8, 256, 0, stream>>>(Bbuf, W2c, Hbuf, N);
    k_aggregate<<<(N + 3) / 4, 256, 0, stream>>>(Hbuf, srclist, rowptr, count, dinv, b2c, Bbuf, N);

    // pool + fc + softmax
    k_pool<<<G, 128, 0, stream>>>(Bbuf, batch, Wfcc, bfcc, d_out, N, G, flags);
}

// Round 5
// 542.193 us; speedup vs baseline: 13.6302x; 1.1031x over previous
//
#include <hip/hip_runtime.h>
#include <hip/hip_bf16.h>

typedef __hip_bfloat16 bf16;
typedef __attribute__((ext_vector_type(8))) short short8;
typedef __attribute__((ext_vector_type(4))) float f32x4;

#define FDIM 64
#define HDIM 128
#define SCHUNK 512

__device__ __forceinline__ float b2f(bf16 v) { return __bfloat162float(v); }
__device__ __forceinline__ float bits2f(unsigned int u) {
    return __uint_as_float(u << 16);
}
__device__ __forceinline__ unsigned short f2bits(float f) {
    bf16 b = __float2bfloat16(f);
    return *reinterpret_cast<unsigned short*>(&b);
}

// ---------------- runtime dtype detection ----------------
__global__ void k_detect(const unsigned short* __restrict__ w1u,
                         const int* __restrict__ edge,
                         const int* __restrict__ batch,
                         int* __restrict__ flags) {
    if (threadIdx.x != 0 || blockIdx.x != 0) return;
    int wild = 0;
    for (int i = 0; i < 256; i += 2) {
        int e = (w1u[i] >> 7) & 0xFF;
        if (e == 0 || e >= 137) wild++;
    }
    flags[0] = (wild > 16) ? 1 : 0;
    int z = 0;
    for (int i = 1; i < 256; i += 2) z += (edge[i] == 0);
    flags[1] = (z > 64) ? 1 : 0;
    z = 0;
    for (int i = 1025; i < 1281; i += 2) z += (batch[i] == 0);
    flags[2] = (z > 64) ? 1 : 0;
}

__global__ void k_convert(const void* __restrict__ src, bf16* __restrict__ dst,
                          int n, const int* __restrict__ flags) {
    int i = blockIdx.x * 256 + threadIdx.x;
    if (i >= n) return;
    if (flags[0]) dst[i] = __float2bfloat16(((const float*)src)[i]);
    else          dst[i] = ((const bf16*)src)[i];
}

__device__ __forceinline__ int edge_word(const int* e, long long logical_idx, int is64) {
    return is64 ? e[2 * logical_idx] : e[logical_idx];
}

// ---------------- CSR build ----------------
__global__ void k_count(const int* __restrict__ edge, int* __restrict__ count, int E,
                        const int* __restrict__ flags) {
    int i = blockIdx.x * blockDim.x + threadIdx.x;
    if (i >= E) return;
    int d = edge_word(edge, (long long)E + i, flags[1]);
    atomicAdd(&count[d], 1);
}

__global__ void k_dinv(const int* __restrict__ count, float* __restrict__ dinv, int N) {
    int i = blockIdx.x * blockDim.x + threadIdx.x;
    if (i < N) dinv[i] = rsqrtf((float)count[i] + 1.0f);
}

__global__ __launch_bounds__(256) void k_scan_partial(const int* __restrict__ count,
                                                      int* __restrict__ parts, int N) {
    __shared__ int red[256];
    int base = blockIdx.x * SCHUNK;
    int t = threadIdx.x;
    int i0 = base + 2 * t, i1 = base + 2 * t + 1;
    int v = 0;
    if (i0 < N) v += count[i0];
    if (i1 < N) v += count[i1];
    red[t] = v;
    __syncthreads();
    for (int s = 128; s > 0; s >>= 1) {
        if (t < s) red[t] += red[t + s];
        __syncthreads();
    }
    if (t == 0) parts[blockIdx.x] = red[0];
}

__global__ __launch_bounds__(256) void k_scan_parts(const int* __restrict__ parts,
                                                    int* __restrict__ partsx, int NP) {
    __shared__ int a[256], b[256];
    int t = threadIdx.x;
    int own = (t < NP) ? parts[t] : 0;
    a[t] = own;
    __syncthreads();
    int* cur = a; int* nxt = b;
    for (int off = 1; off < 256; off <<= 1) {
        int v = cur[t];
        if (t >= off) v += cur[t - off];
        nxt[t] = v;
        __syncthreads();
        int* tmp = cur; cur = nxt; nxt = tmp;
    }
    if (t < NP) partsx[t] = cur[t] - own;
}

__global__ __launch_bounds__(512) void k_scan_final(const int* __restrict__ count,
                                                    const int* __restrict__ partsx,
                                                    int* __restrict__ rowptr, int N) {
    __shared__ int a[512], b[512];
    int t = threadIdx.x;
    int idx = blockIdx.x * SCHUNK + t;
    int own = (idx < N) ? count[idx] : 0;
    a[t] = own;
    __syncthreads();
    int* cur = a; int* nxt = b;
    for (int off = 1; off < 512; off <<= 1) {
        int v = cur[t];
        if (t >= off) v += cur[t - off];
        nxt[t] = v;
        __syncthreads();
        int* tmp = cur; cur = nxt; nxt = tmp;
    }
    if (idx < N) rowptr[idx] = cur[t] - own + partsx[blockIdx.x];
}

__global__ void k_fill(const int* __restrict__ edge, const int* __restrict__ rowptr,
                       int* __restrict__ cursor, int* __restrict__ srclist, int E,
                       const int* __restrict__ flags) {
    int i = blockIdx.x * blockDim.x + threadIdx.x;
    if (i >= E) return;
    int is64 = flags[1];
    int s = edge_word(edge, i, is64);
    int d = edge_word(edge, (long long)E + i, is64);
    int pos = rowptr[d] + atomicAdd(&cursor[d], 1);
    srclist[pos] = s;
}

// ---------------- MFMA GEMM1: h1[N,128](bf16) = x[N,64] @ W1[64,128] ----------------
// block: 256 thr / 4 waves -> 64 rows x 128 cols. K=64 (2 chunks of 32).
#define K1PAD 72   // 64+8: 144B row stride = 9*16B, bank shift 4/row
__global__ __launch_bounds__(256) void k_gemm1(const void* __restrict__ x,
                                               const bf16* __restrict__ W1,
                                               bf16* __restrict__ h1, int N,
                                               const int* __restrict__ flags) {
    __shared__ bf16 As[64 * K1PAD];        // 9 KB
    __shared__ bf16 Wt[HDIM * K1PAD];      // 18 KB, Wt[n][k] = W1[k*128+n]
    int tid = threadIdx.x;
    int base = blockIdx.x * 64;
    // stage Wt (transposed)
    for (int i = tid; i < HDIM * FDIM; i += 256) {
        int n = i >> 6, k = i & 63;
        Wt[n * K1PAD + k] = W1[k * HDIM + n];
    }
    // stage A (convert f32->bf16 if needed)
    if (flags[0]) {
        const float4* xf = (const float4*)x;
        for (int i = tid; i < 64 * 16; i += 256) {
            int r = i >> 4, c = i & 15;
            int gr = base + r; if (gr >= N) gr = N - 1;
            float4 v = xf[(size_t)gr * 16 + c];
            unsigned int p0 = ((unsigned int)f2bits(v.y) << 16) | f2bits(v.x);
            unsigned int p1 = ((unsigned int)f2bits(v.w) << 16) | f2bits(v.z);
            *(uint2*)&As[r * K1PAD + c * 4] = make_uint2(p0, p1);
        }
    } else {
        const uint4* xb = (const uint4*)x;   // 8 bf16
        for (int i = tid; i < 64 * 8; i += 256) {
            int r = i >> 3, c = i & 7;
            int gr = base + r; if (gr >= N) gr = N - 1;
            *(uint4*)&As[r * K1PAD + c * 8] = xb[(size_t)gr * 8 + c];
        }
    }
    __syncthreads();
    int wid = tid >> 6, lane = tid & 63;
    int l15 = lane & 15, q = lane >> 4;
    int m0 = wid * 16;
    short8 af[2];
#pragma unroll
    for (int kc = 0; kc < 2; kc++)
        af[kc] = *(const short8*)&As[(m0 + l15) * K1PAD + kc * 32 + q * 8];
    f32x4 acc[8];
#pragma unroll
    for (int nt = 0; nt < 8; nt++) {
        acc[nt] = (f32x4){0.f, 0.f, 0.f, 0.f};
#pragma unroll
        for (int kc = 0; kc < 2; kc++) {
            short8 bf = *(const short8*)&Wt[(nt * 16 + l15) * K1PAD + kc * 32 + q * 8];
            acc[nt] = __builtin_amdgcn_mfma_f32_16x16x32_bf16(af[kc], bf, acc[nt], 0, 0, 0);
        }
    }
#pragma unroll
    for (int nt = 0; nt < 8; nt++) {
        int col = nt * 16 + l15;
#pragma unroll
        for (int r = 0; r < 4; r++) {
            int gr = base + m0 + q * 4 + r;
            if (gr < N) h1[(size_t)gr * HDIM + col] = __float2bfloat16(acc[nt][r]);
        }
    }
}

// ---------------- MFMA GEMM2: h2[N,128](bf16) = act[N,128](bf16) @ W2[128,128] ----------------
#define K2PAD 136  // 128+8: 272B row stride = 17*16B, bank shift 4/row
__global__ __launch_bounds__(256) void k_gemm2(const bf16* __restrict__ xin,
                                               const bf16* __restrict__ W2,
                                               bf16* __restrict__ outp, int N) {
    __shared__ bf16 As[64 * K2PAD];        // 17 KB
    __shared__ bf16 Wt[HDIM * K2PAD];      // 34 KB
    int tid = threadIdx.x;
    int base = blockIdx.x * 64;
    for (int i = tid; i < HDIM * HDIM; i += 256) {
        int n = i >> 7, k = i & 127;
        Wt[n * K2PAD + k] = W2[k * HDIM + n];
    }
    const uint4* xb = (const uint4*)xin;   // 8 bf16 per uint4
    for (int i = tid; i < 64 * 16; i += 256) {
        int r = i >> 4, c = i & 15;
        int gr = base + r; if (gr >= N) gr = N - 1;
        *(uint4*)&As[r * K2PAD + c * 8] = xb[(size_t)gr * 16 + c];
    }
    __syncthreads();
    int wid = tid >> 6, lane = tid & 63;
    int l15 = lane & 15, q = lane >> 4;
    int m0 = wid * 16;
    short8 af[4];
#pragma unroll
    for (int kc = 0; kc < 4; kc++)
        af[kc] = *(const short8*)&As[(m0 + l15) * K2PAD + kc * 32 + q * 8];
    f32x4 acc[8];
#pragma unroll
    for (int nt = 0; nt < 8; nt++) {
        acc[nt] = (f32x4){0.f, 0.f, 0.f, 0.f};
#pragma unroll
        for (int kc = 0; kc < 4; kc++) {
            short8 bf = *(const short8*)&Wt[(nt * 16 + l15) * K2PAD + kc * 32 + q * 8];
            acc[nt] = __builtin_amdgcn_mfma_f32_16x16x32_bf16(af[kc], bf, acc[nt], 0, 0, 0);
        }
    }
#pragma unroll
    for (int nt = 0; nt < 8; nt++) {
        int col = nt * 16 + l15;
#pragma unroll
        for (int r = 0; r < 4; r++) {
            int gr = base + m0 + q * 4 + r;
            if (gr < N) outp[(size_t)gr * HDIM + col] = __float2bfloat16(acc[nt][r]);
        }
    }
}

// ---------------- aggregate ----------------
__global__ __launch_bounds__(256) void k_aggregate(const bf16* __restrict__ h,
                                                   const int* __restrict__ srclist,
                                                   const int* __restrict__ rowptr,
                                                   const int* __restrict__ count,
                                                   const float* __restrict__ dinv,
                                                   const bf16* __restrict__ bias,
                                                   bf16* __restrict__ outb, int N) {
    int wid = threadIdx.x >> 6;
    int lane = threadIdx.x & 63;
    int i = blockIdx.x * 4 + wid;
    if (i >= N) return;
    int start = rowptr[i];
    int cnt = count[i];
    float di = dinv[i];
    const unsigned int* hrow = (const unsigned int*)h;
    float a0 = 0.f, a1 = 0.f;
    int j = 0;
    for (; j + 1 < cnt; j += 2) {
        int s0 = srclist[start + j];
        int s1 = srclist[start + j + 1];
        unsigned int v0 = hrow[(size_t)s0 * 64 + lane];
        unsigned int v1 = hrow[(size_t)s1 * 64 + lane];
        float d0 = dinv[s0], d1 = dinv[s1];
        a0 += bits2f(v0 & 0xFFFFu) * d0;
        a1 += bits2f(v0 >> 16) * d0;
        a0 += bits2f(v1 & 0xFFFFu) * d1;
        a1 += bits2f(v1 >> 16) * d1;
    }
    if (j < cnt) {
        int s0 = srclist[start + j];
        unsigned int v0 = hrow[(size_t)s0 * 64 + lane];
        float d0 = dinv[s0];
        a0 += bits2f(v0 & 0xFFFFu) * d0;
        a1 += bits2f(v0 >> 16) * d0;
    }
    unsigned int vs = hrow[(size_t)i * 64 + lane];
    float self = di * di;
    float b0 = b2f(bias[2 * lane]);
    float b1 = b2f(bias[2 * lane + 1]);
    float r0 = fmaxf(di * a0 + bits2f(vs & 0xFFFFu) * self + b0, 0.f);
    float r1 = fmaxf(di * a1 + bits2f(vs >> 16) * self + b1, 0.f);
    unsigned int packed = ((unsigned int)f2bits(r1) << 16) | f2bits(r0);
    ((unsigned int*)outb)[(size_t)i * 64 + lane] = packed;
}

// ---------------- pool + fc + softmax ----------------
__global__ __launch_bounds__(128) void k_pool(const bf16* __restrict__ hact,
                                              const int* __restrict__ batch,
                                              const bf16* __restrict__ Wfc,
                                              const bf16* __restrict__ bfc,
                                              void* __restrict__ out, int N, int G,
                                              const int* __restrict__ flags) {
    int g = blockIdx.x;
    int t = threadIdx.x;
    int is64 = flags[2];
    int lo = 0, hi = N;
    while (lo < hi) {
        int mid = (lo + hi) >> 1;
        int bm = is64 ? batch[2 * mid] : batch[mid];
        if (bm < g) lo = mid + 1; else hi = mid;
    }
    int start = lo;
    hi = N;
    while (lo < hi) {
        int mid = (lo + hi) >> 1;
        int bm = is64 ? batch[2 * mid] : batch[mid];
        if (bm < g + 1) lo = mid + 1; else hi = mid;
    }
    int end = lo;

    float sum = 0.f;
    for (int r = start; r < end; r++) sum += b2f(hact[(size_t)r * HDIM + t]);
    float cnt = (float)(end - start);
    float mean = sum / fmaxf(cnt, 1.0f);

    __shared__ float l0[128];
    __shared__ float l1[128];
    l0[t] = mean * b2f(Wfc[t * 2 + 0]);
    l1[t] = mean * b2f(Wfc[t * 2 + 1]);
    __syncthreads();
    for (int sft = 64; sft > 0; sft >>= 1) {
        if (t < sft) { l0[t] += l0[t + sft]; l1[t] += l1[t + sft]; }
        __syncthreads();
    }
    if (t == 0) {
        float z0 = l0[0] + b2f(bfc[0]);
        float z1 = l1[0] + b2f(bfc[1]);
        float m = fmaxf(z0, z1);
        float e0 = expf(z0 - m), e1 = expf(z1 - m);
        float s = e0 + e1;
        float p0 = e0 / s, p1 = e1 / s;
        if (flags[0]) {
            ((float*)out)[g * 2 + 0] = p0;
            ((float*)out)[g * 2 + 1] = p1;
        } else {
            ((bf16*)out)[g * 2 + 0] = __float2bfloat16(p0);
            ((bf16*)out)[g * 2 + 1] = __float2bfloat16(p1);
        }
    }
}

extern "C" void kernel_launch(void* const* d_in, const int* in_sizes, int n_in,
                              void* d_out, int out_size, void* d_ws, size_t ws_size,
                              hipStream_t stream) {
    const void* x    = d_in[0];
    const int*  edge = (const int*)d_in[1];
    const int*  batch= (const int*)d_in[2];
    const void* W1  = d_in[4];
    const void* b1  = d_in[5];
    const void* W2  = d_in[6];
    const void* b2  = d_in[7];
    const void* Wfc = d_in[8];
    const void* bfc = d_in[9];

    int N = in_sizes[0] / FDIM;   // 100000
    int E = in_sizes[1] / 2;      // 1000000
    int G = out_size / 2;         // 512
    int NP = (N + SCHUNK - 1) / SCHUNK;

    int*   flags  = (int*)d_ws;
    float* dinv   = (float*)((char*)d_ws + 64);
    int*   count  = (int*)(dinv + N);
    int*   rowptr = count + N;
    int*   cursor = rowptr + N;
    int*   parts  = cursor + N;
    int*   partsx = parts + 256;
    int*   srclist= partsx + 256;
    bf16*  Hbuf   = (bf16*)(srclist + E);
    bf16*  Bbuf   = Hbuf + (size_t)N * HDIM;
    bf16*  W1c    = Bbuf + (size_t)N * HDIM;
    bf16*  b1c    = W1c + FDIM * HDIM;
    bf16*  W2c    = b1c + HDIM;
    bf16*  b2c    = W2c + HDIM * HDIM;
    bf16*  Wfcc   = b2c + HDIM;
    bf16*  bfcc   = Wfcc + 256;

    k_detect<<<1, 64, 0, stream>>>((const unsigned short*)W1, edge, batch, flags);
    k_convert<<<(FDIM * HDIM + 255) / 256, 256, 0, stream>>>(W1, W1c, FDIM * HDIM, flags);
    k_convert<<<1, 256, 0, stream>>>(b1, b1c, HDIM, flags);
    k_convert<<<(HDIM * HDIM + 255) / 256, 256, 0, stream>>>(W2, W2c, HDIM * HDIM, flags);
    k_convert<<<1, 256, 0, stream>>>(b2, b2c, HDIM, flags);
    k_convert<<<1, 256, 0, stream>>>(Wfc, Wfcc, 256, flags);
    k_convert<<<1, 256, 0, stream>>>(bfc, bfcc, 2, flags);

    hipMemsetAsync(count, 0, (size_t)N * sizeof(int), stream);
    hipMemsetAsync(cursor, 0, (size_t)N * sizeof(int), stream);
    k_count<<<(E + 255) / 256, 256, 0, stream>>>(edge, count, E, flags);
    k_dinv<<<(N + 255) / 256, 256, 0, stream>>>(count, dinv, N);
    k_scan_partial<<<NP, 256, 0, stream>>>(count, parts, N);
    k_scan_parts<<<1, 256, 0, stream>>>(parts, partsx, NP);
    k_scan_final<<<NP, 512, 0, stream>>>(count, partsx, rowptr, N);
    k_fill<<<(E + 255) / 256, 256, 0, stream>>>(edge, rowptr, cursor, srclist, E, flags);

    // layer 1
    k_gemm1<<<(N + 63) / 64, 256, 0, stream>>>(x, W1c, Hbuf, N, flags);
    k_aggregate<<<(N + 3) / 4, 256, 0, stream>>>(Hbuf, srclist, rowptr, count, dinv, b1c, Bbuf, N);

    // layer 2
    k_gemm2<<<(N + 63) / 64, 256, 0, stream>>>(Bbuf, W2c, Hbuf, N);
    k_aggregate<<<(N + 3) / 4, 256, 0, stream>>>(Hbuf, srclist, rowptr, count, dinv, b2c, Bbuf, N);

    // pool + fc + softmax
    k_pool<<<G, 128, 0, stream>>>(Bbuf, batch, Wfcc, bfcc, d_out, N, G, flags);
}

// Round 6
// 467.909 us; speedup vs baseline: 15.7941x; 1.1588x over previous
//
#include <hip/hip_runtime.h>
#include <hip/hip_bf16.h>

typedef __hip_bfloat16 bf16;
typedef __attribute__((ext_vector_type(8))) short short8;
typedef __attribute__((ext_vector_type(4))) float f32x4;

#define FDIM 64
#define HDIM 128
#define SCHUNK 512

__device__ __forceinline__ float b2f(bf16 v) { return __bfloat162float(v); }
__device__ __forceinline__ float bits2f(unsigned int u) {
    return __uint_as_float(u << 16);
}
__device__ __forceinline__ unsigned short f2bits(float f) {
    bf16 b = __float2bfloat16(f);
    return *reinterpret_cast<unsigned short*>(&b);
}

// ---------------- prep: detect dtypes + convert weights + transpose ----------------
// single block, 256 threads. Outputs: flags, W1c,b1c,W2c,b2c,Wfcc,bfcc, W1t,W2t.
__global__ __launch_bounds__(256) void k_prep(const void* __restrict__ W1,
                                              const void* __restrict__ b1,
                                              const void* __restrict__ W2,
                                              const void* __restrict__ b2,
                                              const void* __restrict__ Wfc,
                                              const void* __restrict__ bfc,
                                              const int* __restrict__ edge,
                                              const int* __restrict__ batch,
                                              int* __restrict__ flags,
                                              bf16* __restrict__ W1c, bf16* __restrict__ b1c,
                                              bf16* __restrict__ W2c, bf16* __restrict__ b2c,
                                              bf16* __restrict__ Wfcc, bf16* __restrict__ bfcc,
                                              bf16* __restrict__ W1t, bf16* __restrict__ W2t) {
    __shared__ int sf[4];
    int tid = threadIdx.x;
    if (tid == 0) {
        const unsigned short* w1u = (const unsigned short*)W1;
        int wild = 0;
        for (int i = 0; i < 256; i += 2) {
            int e = (w1u[i] >> 7) & 0xFF;
            if (e == 0 || e >= 137) wild++;
        }
        sf[0] = (wild > 16) ? 1 : 0;
        int z = 0;
        for (int i = 1; i < 256; i += 2) z += (edge[i] == 0);
        sf[1] = (z > 64) ? 1 : 0;
        z = 0;
        for (int i = 1025; i < 1281; i += 2) z += (batch[i] == 0);
        sf[2] = (z > 64) ? 1 : 0;
        flags[0] = sf[0]; flags[1] = sf[1]; flags[2] = sf[2];
    }
    __syncthreads();
    int f0 = sf[0];
#define CONV(src, dst, n) \
    for (int i = tid; i < (n); i += 256) { \
        if (f0) dst[i] = __float2bfloat16(((const float*)src)[i]); \
        else    dst[i] = ((const bf16*)src)[i]; \
    }
    CONV(W1, W1c, FDIM * HDIM)
    CONV(b1, b1c, HDIM)
    CONV(W2, W2c, HDIM * HDIM)
    CONV(b2, b2c, HDIM)
    CONV(Wfc, Wfcc, HDIM * 2)
    CONV(bfc, bfcc, 2)
#undef CONV
    __syncthreads();
    // transposes: W1t[n*64+k] = W1c[k*128+n]; W2t[n*128+k] = W2c[k*128+n]
    for (int i = tid; i < FDIM * HDIM; i += 256) {
        int n = i >> 6, k = i & 63;
        W1t[i] = W1c[k * HDIM + n];
    }
    for (int i = tid; i < HDIM * HDIM; i += 256) {
        int n = i >> 7, k = i & 127;
        W2t[i] = W2c[k * HDIM + n];
    }
}

__device__ __forceinline__ int edge_word(const int* e, long long logical_idx, int is64) {
    return is64 ? e[2 * logical_idx] : e[logical_idx];
}

// ---------------- CSR build ----------------
__global__ void k_count(const int* __restrict__ edge, int* __restrict__ count, int E,
                        const int* __restrict__ flags) {
    int i = blockIdx.x * blockDim.x + threadIdx.x;
    if (i >= E) return;
    int d = edge_word(edge, (long long)E + i, flags[1]);
    atomicAdd(&count[d], 1);
}

__global__ __launch_bounds__(256) void k_scan_partial(const int* __restrict__ count,
                                                      int* __restrict__ parts, int N) {
    __shared__ int red[256];
    int base = blockIdx.x * SCHUNK;
    int t = threadIdx.x;
    int i0 = base + 2 * t, i1 = base + 2 * t + 1;
    int v = 0;
    if (i0 < N) v += count[i0];
    if (i1 < N) v += count[i1];
    red[t] = v;
    __syncthreads();
    for (int s = 128; s > 0; s >>= 1) {
        if (t < s) red[t] += red[t + s];
        __syncthreads();
    }
    if (t == 0) parts[blockIdx.x] = red[0];
}

__global__ __launch_bounds__(256) void k_scan_parts(const int* __restrict__ parts,
                                                    int* __restrict__ partsx, int NP) {
    __shared__ int a[256], b[256];
    int t = threadIdx.x;
    int own = (t < NP) ? parts[t] : 0;
    a[t] = own;
    __syncthreads();
    int* cur = a; int* nxt = b;
    for (int off = 1; off < 256; off <<= 1) {
        int v = cur[t];
        if (t >= off) v += cur[t - off];
        nxt[t] = v;
        __syncthreads();
        int* tmp = cur; cur = nxt; nxt = tmp;
    }
    if (t < NP) partsx[t] = cur[t] - own;
}

// per-chunk exclusive scan + chunk offset -> rowptr; also dinv = rsqrt(count+1)
__global__ __launch_bounds__(512) void k_scan_final(const int* __restrict__ count,
                                                    const int* __restrict__ partsx,
                                                    int* __restrict__ rowptr,
                                                    float* __restrict__ dinv, int N) {
    __shared__ int a[512], b[512];
    int t = threadIdx.x;
    int idx = blockIdx.x * SCHUNK + t;
    int own = (idx < N) ? count[idx] : 0;
    a[t] = own;
    __syncthreads();
    int* cur = a; int* nxt = b;
    for (int off = 1; off < 512; off <<= 1) {
        int v = cur[t];
        if (t >= off) v += cur[t - off];
        nxt[t] = v;
        __syncthreads();
        int* tmp = cur; cur = nxt; nxt = tmp;
    }
    if (idx < N) {
        rowptr[idx] = cur[t] - own + partsx[blockIdx.x];
        dinv[idx] = rsqrtf((float)own + 1.0f);
    }
}

__global__ void k_fill(const int* __restrict__ edge, const int* __restrict__ rowptr,
                       int* __restrict__ cursor, int* __restrict__ srclist, int E,
                       const int* __restrict__ flags) {
    int i = blockIdx.x * blockDim.x + threadIdx.x;
    if (i >= E) return;
    int is64 = flags[1];
    int s = edge_word(edge, i, is64);
    int d = edge_word(edge, (long long)E + i, is64);
    int pos = rowptr[d] + atomicAdd(&cursor[d], 1);
    srclist[pos] = s;
}

// ---------------- MFMA GEMM1: h1[N,128](bf16) = x[N,64] @ W1[64,128] ----------------
#define K1PAD 72   // 64+8: 144B row stride = 9*16B
__global__ __launch_bounds__(256) void k_gemm1(const void* __restrict__ x,
                                               const bf16* __restrict__ W1t,
                                               bf16* __restrict__ h1, int N,
                                               const int* __restrict__ flags) {
    __shared__ bf16 As[64 * K1PAD];
    __shared__ bf16 Wt[HDIM * K1PAD];
    int tid = threadIdx.x;
    int base = blockIdx.x * 64;
    // stage Wt from pre-transposed W1t: row n = 8 uint4
    {
        const uint4* wsrc = (const uint4*)W1t;
        for (int i = tid; i < HDIM * 8; i += 256) {
            int n = i >> 3, c = i & 7;
            *(uint4*)&Wt[n * K1PAD + c * 8] = wsrc[n * 8 + c];
        }
    }
    if (flags[0]) {
        const float4* xf = (const float4*)x;
        for (int i = tid; i < 64 * 16; i += 256) {
            int r = i >> 4, c = i & 15;
            int gr = base + r; if (gr >= N) gr = N - 1;
            float4 v = xf[(size_t)gr * 16 + c];
            unsigned int p0 = ((unsigned int)f2bits(v.y) << 16) | f2bits(v.x);
            unsigned int p1 = ((unsigned int)f2bits(v.w) << 16) | f2bits(v.z);
            *(uint2*)&As[r * K1PAD + c * 4] = make_uint2(p0, p1);
        }
    } else {
        const uint4* xb = (const uint4*)x;
        for (int i = tid; i < 64 * 8; i += 256) {
            int r = i >> 3, c = i & 7;
            int gr = base + r; if (gr >= N) gr = N - 1;
            *(uint4*)&As[r * K1PAD + c * 8] = xb[(size_t)gr * 8 + c];
        }
    }
    __syncthreads();
    int wid = tid >> 6, lane = tid & 63;
    int l15 = lane & 15, q = lane >> 4;
    int m0 = wid * 16;
    short8 af[2];
#pragma unroll
    for (int kc = 0; kc < 2; kc++)
        af[kc] = *(const short8*)&As[(m0 + l15) * K1PAD + kc * 32 + q * 8];
    f32x4 acc[8];
#pragma unroll
    for (int nt = 0; nt < 8; nt++) {
        acc[nt] = (f32x4){0.f, 0.f, 0.f, 0.f};
#pragma unroll
        for (int kc = 0; kc < 2; kc++) {
            short8 bf = *(const short8*)&Wt[(nt * 16 + l15) * K1PAD + kc * 32 + q * 8];
            acc[nt] = __builtin_amdgcn_mfma_f32_16x16x32_bf16(af[kc], bf, acc[nt], 0, 0, 0);
        }
    }
#pragma unroll
    for (int nt = 0; nt < 8; nt++) {
        int col = nt * 16 + l15;
#pragma unroll
        for (int r = 0; r < 4; r++) {
            int gr = base + m0 + q * 4 + r;
            if (gr < N) h1[(size_t)gr * HDIM + col] = __float2bfloat16(acc[nt][r]);
        }
    }
}

// ---------------- MFMA GEMM2: h2[N,128](bf16) = act[N,128](bf16) @ W2[128,128] ----------------
#define K2PAD 136  // 128+8: 272B row stride = 17*16B
__global__ __launch_bounds__(256) void k_gemm2(const bf16* __restrict__ xin,
                                               const bf16* __restrict__ W2t,
                                               bf16* __restrict__ outp, int N) {
    __shared__ bf16 As[64 * K2PAD];
    __shared__ bf16 Wt[HDIM * K2PAD];
    int tid = threadIdx.x;
    int base = blockIdx.x * 64;
    {
        const uint4* wsrc = (const uint4*)W2t;
        for (int i = tid; i < HDIM * 16; i += 256) {
            int n = i >> 4, c = i & 15;
            *(uint4*)&Wt[n * K2PAD + c * 8] = wsrc[n * 16 + c];
        }
    }
    const uint4* xb = (const uint4*)xin;
    for (int i = tid; i < 64 * 16; i += 256) {
        int r = i >> 4, c = i & 15;
        int gr = base + r; if (gr >= N) gr = N - 1;
        *(uint4*)&As[r * K2PAD + c * 8] = xb[(size_t)gr * 16 + c];
    }
    __syncthreads();
    int wid = tid >> 6, lane = tid & 63;
    int l15 = lane & 15, q = lane >> 4;
    int m0 = wid * 16;
    short8 af[4];
#pragma unroll
    for (int kc = 0; kc < 4; kc++)
        af[kc] = *(const short8*)&As[(m0 + l15) * K2PAD + kc * 32 + q * 8];
    f32x4 acc[8];
#pragma unroll
    for (int nt = 0; nt < 8; nt++) {
        acc[nt] = (f32x4){0.f, 0.f, 0.f, 0.f};
#pragma unroll
        for (int kc = 0; kc < 4; kc++) {
            short8 bf = *(const short8*)&Wt[(nt * 16 + l15) * K2PAD + kc * 32 + q * 8];
            acc[nt] = __builtin_amdgcn_mfma_f32_16x16x32_bf16(af[kc], bf, acc[nt], 0, 0, 0);
        }
    }
#pragma unroll
    for (int nt = 0; nt < 8; nt++) {
        int col = nt * 16 + l15;
#pragma unroll
        for (int r = 0; r < 4; r++) {
            int gr = base + m0 + q * 4 + r;
            if (gr < N) outp[(size_t)gr * HDIM + col] = __float2bfloat16(acc[nt][r]);
        }
    }
}

// ---------------- aggregate (shfl-batched neighbor prefetch) ----------------
// one wave per node; lane holds features {2l,2l+1}. Neighbor indices + dinv
// prefetched 64-at-a-time (coalesced), broadcast via shfl; 4-deep unroll with
// independent accumulator pairs for outstanding-gather ILP.
__global__ __launch_bounds__(256) void k_aggregate(const bf16* __restrict__ h,
                                                   const int* __restrict__ srclist,
                                                   const int* __restrict__ rowptr,
                                                   const int* __restrict__ count,
                                                   const float* __restrict__ dinv,
                                                   const bf16* __restrict__ bias,
                                                   bf16* __restrict__ outb, int N) {
    int wid = threadIdx.x >> 6;
    int lane = threadIdx.x & 63;
    int i = blockIdx.x * 4 + wid;
    if (i >= N) return;
    int start = rowptr[i];
    int cnt = count[i];
    float di = dinv[i];
    const unsigned int* hrow = (const unsigned int*)h;
    float a0 = 0.f, a1 = 0.f, p0 = 0.f, p1 = 0.f, q0 = 0.f, q1 = 0.f, r0a = 0.f, r1a = 0.f;
    for (int bj = 0; bj < cnt; bj += 64) {
        int m = cnt - bj; if (m > 64) m = 64;
        int idx = bj + ((lane < m) ? lane : (m - 1));
        int sv = srclist[start + idx];
        float dvv = dinv[sv];
        int j = 0;
        for (; j + 4 <= m; j += 4) {
            int s0 = __shfl(sv, j), s1 = __shfl(sv, j + 1);
            int s2 = __shfl(sv, j + 2), s3 = __shfl(sv, j + 3);
            float e0 = __shfl(dvv, j), e1 = __shfl(dvv, j + 1);
            float e2 = __shfl(dvv, j + 2), e3 = __shfl(dvv, j + 3);
            unsigned int v0 = hrow[(size_t)s0 * 64 + lane];
            unsigned int v1 = hrow[(size_t)s1 * 64 + lane];
            unsigned int v2 = hrow[(size_t)s2 * 64 + lane];
            unsigned int v3 = hrow[(size_t)s3 * 64 + lane];
            a0 += bits2f(v0 & 0xFFFFu) * e0; a1 += bits2f(v0 >> 16) * e0;
            p0 += bits2f(v1 & 0xFFFFu) * e1; p1 += bits2f(v1 >> 16) * e1;
            q0 += bits2f(v2 & 0xFFFFu) * e2; q1 += bits2f(v2 >> 16) * e2;
            r0a += bits2f(v3 & 0xFFFFu) * e3; r1a += bits2f(v3 >> 16) * e3;
        }
        for (; j < m; j++) {
            int s0 = __shfl(sv, j);
            float e0 = __shfl(dvv, j);
            unsigned int v0 = hrow[(size_t)s0 * 64 + lane];
            a0 += bits2f(v0 & 0xFFFFu) * e0; a1 += bits2f(v0 >> 16) * e0;
        }
    }
    a0 = (a0 + p0) + (q0 + r0a);
    a1 = (a1 + p1) + (q1 + r1a);
    unsigned int vs = hrow[(size_t)i * 64 + lane];
    float self = di * di;
    float b0 = b2f(bias[2 * lane]);
    float b1 = b2f(bias[2 * lane + 1]);
    float o0 = fmaxf(di * a0 + bits2f(vs & 0xFFFFu) * self + b0, 0.f);
    float o1 = fmaxf(di * a1 + bits2f(vs >> 16) * self + b1, 0.f);
    unsigned int packed = ((unsigned int)f2bits(o1) << 16) | f2bits(o0);
    ((unsigned int*)outb)[(size_t)i * 64 + lane] = packed;
}

// ---------------- pool + fc + softmax ----------------
__global__ __launch_bounds__(128) void k_pool(const bf16* __restrict__ hact,
                                              const int* __restrict__ batch,
                                              const bf16* __restrict__ Wfc,
                                              const bf16* __restrict__ bfc,
                                              void* __restrict__ out, int N, int G,
                                              const int* __restrict__ flags) {
    int g = blockIdx.x;
    int t = threadIdx.x;
    int is64 = flags[2];
    int lo = 0, hi = N;
    while (lo < hi) {
        int mid = (lo + hi) >> 1;
        int bm = is64 ? batch[2 * mid] : batch[mid];
        if (bm < g) lo = mid + 1; else hi = mid;
    }
    int start = lo;
    hi = N;
    while (lo < hi) {
        int mid = (lo + hi) >> 1;
        int bm = is64 ? batch[2 * mid] : batch[mid];
        if (bm < g + 1) lo = mid + 1; else hi = mid;
    }
    int end = lo;

    float sum = 0.f;
    for (int r = start; r < end; r++) sum += b2f(hact[(size_t)r * HDIM + t]);
    float cnt = (float)(end - start);
    float mean = sum / fmaxf(cnt, 1.0f);

    __shared__ float l0[128];
    __shared__ float l1[128];
    l0[t] = mean * b2f(Wfc[t * 2 + 0]);
    l1[t] = mean * b2f(Wfc[t * 2 + 1]);
    __syncthreads();
    for (int sft = 64; sft > 0; sft >>= 1) {
        if (t < sft) { l0[t] += l0[t + sft]; l1[t] += l1[t + sft]; }
        __syncthreads();
    }
    if (t == 0) {
        float z0 = l0[0] + b2f(bfc[0]);
        float z1 = l1[0] + b2f(bfc[1]);
        float m = fmaxf(z0, z1);
        float e0 = expf(z0 - m), e1 = expf(z1 - m);
        float s = e0 + e1;
        float pr0 = e0 / s, pr1 = e1 / s;
        if (flags[0]) {
            ((float*)out)[g * 2 + 0] = pr0;
            ((float*)out)[g * 2 + 1] = pr1;
        } else {
            ((bf16*)out)[g * 2 + 0] = __float2bfloat16(pr0);
            ((bf16*)out)[g * 2 + 1] = __float2bfloat16(pr1);
        }
    }
}

extern "C" void kernel_launch(void* const* d_in, const int* in_sizes, int n_in,
                              void* d_out, int out_size, void* d_ws, size_t ws_size,
                              hipStream_t stream) {
    const void* x    = d_in[0];
    const int*  edge = (const int*)d_in[1];
    const int*  batch= (const int*)d_in[2];
    const void* W1  = d_in[4];
    const void* b1  = d_in[5];
    const void* W2  = d_in[6];
    const void* b2  = d_in[7];
    const void* Wfc = d_in[8];
    const void* bfc = d_in[9];

    int N = in_sizes[0] / FDIM;   // 100000
    int E = in_sizes[1] / 2;      // 1000000
    int G = out_size / 2;         // 512
    int NP = (N + SCHUNK - 1) / SCHUNK;

    int*   flags  = (int*)d_ws;                          // 64 B
    float* dinv   = (float*)((char*)d_ws + 64);          // N
    int*   count  = (int*)(dinv + N);                    // N  (count+cursor adjacent!)
    int*   cursor = count + N;                           // N
    int*   rowptr = cursor + N;                          // N
    int*   parts  = rowptr + N;                          // 256
    int*   partsx = parts + 256;                         // 256
    int*   srclist= partsx + 256;                        // E
    bf16*  Hbuf   = (bf16*)(srclist + E);                // N*128
    bf16*  Bbuf   = Hbuf + (size_t)N * HDIM;             // N*128
    bf16*  W1c    = Bbuf + (size_t)N * HDIM;             // 8192
    bf16*  b1c    = W1c + FDIM * HDIM;                   // 128
    bf16*  W2c    = b1c + HDIM;                          // 16384
    bf16*  b2c    = W2c + HDIM * HDIM;                   // 128
    bf16*  Wfcc   = b2c + HDIM;                          // 256
    bf16*  bfcc   = Wfcc + 256;                          // 64 (pad)
    bf16*  W1t    = bfcc + 64;                           // 8192
    bf16*  W2t    = W1t + FDIM * HDIM;                   // 16384

    k_prep<<<1, 256, 0, stream>>>(W1, b1, W2, b2, Wfc, bfc, edge, batch, flags,
                                  W1c, b1c, W2c, b2c, Wfcc, bfcc, W1t, W2t);

    hipMemsetAsync(count, 0, (size_t)2 * N * sizeof(int), stream);  // count+cursor
    k_count<<<(E + 255) / 256, 256, 0, stream>>>(edge, count, E, flags);
    k_scan_partial<<<NP, 256, 0, stream>>>(count, parts, N);
    k_scan_parts<<<1, 256, 0, stream>>>(parts, partsx, NP);
    k_scan_final<<<NP, 512, 0, stream>>>(count, partsx, rowptr, dinv, N);
    k_fill<<<(E + 255) / 256, 256, 0, stream>>>(edge, rowptr, cursor, srclist, E, flags);

    // layer 1
    k_gemm1<<<(N + 63) / 64, 256, 0, stream>>>(x, W1t, Hbuf, N, flags);
    k_aggregate<<<(N + 3) / 4, 256, 0, stream>>>(Hbuf, srclist, rowptr, count, dinv, b1c, Bbuf, N);

    // layer 2
    k_gemm2<<<(N + 63) / 64, 256, 0, stream>>>(Bbuf, W2t, Hbuf, N);
    k_aggregate<<<(N + 3) / 4, 256, 0, stream>>>(Hbuf, srclist, rowptr, count, dinv, b2c, Bbuf, N);

    // pool + fc + softmax
    k_pool<<<G, 128, 0, stream>>>(Bbuf, batch, Wfcc, bfcc, d_out, N, G, flags);
}

// Round 8
// 396.451 us; speedup vs baseline: 18.6409x; 1.1802x over previous
//
#include <hip/hip_runtime.h>
#include <hip/hip_bf16.h>

typedef __hip_bfloat16 bf16;
typedef __attribute__((ext_vector_type(8))) short short8;
typedef __attribute__((ext_vector_type(4))) float f32x4;

#define FDIM 64
#define HDIM 128
#define SCHUNK 512
#define PROWS 256

__device__ __forceinline__ float b2f(bf16 v) { return __bfloat162float(v); }
__device__ __forceinline__ float bits2f(unsigned int u) {
    return __uint_as_float(u << 16);
}
__device__ __forceinline__ unsigned short f2bits(float f) {
    bf16 b = __float2bfloat16(f);
    return *reinterpret_cast<unsigned short*>(&b);
}

// ---------------- flags: parallel dtype detection (1 block, 3 waves) ----------------
__global__ __launch_bounds__(192) void k_prep_flags(const unsigned short* __restrict__ w1u,
                                                    const int* __restrict__ edge,
                                                    const int* __restrict__ batch,
                                                    int* __restrict__ flags) {
    int wave = threadIdx.x >> 6, lane = threadIdx.x & 63;
    if (wave == 0) {
        int wild = 0;
#pragma unroll
        for (int r = 0; r < 2; r++) {
            int i = 2 * lane + 128 * r;            // even indices 0..254
            int e = (w1u[i] >> 7) & 0xFF;
            wild += (e == 0 || e >= 137) ? 1 : 0;
        }
        for (int s = 32; s; s >>= 1) wild += __shfl_down(wild, s);
        if (lane == 0) flags[0] = (wild > 16) ? 1 : 0;
    } else if (wave == 1) {
        int z = 0;
#pragma unroll
        for (int r = 0; r < 2; r++) {
            int i = 2 * lane + 1 + 128 * r;        // odd indices 1..255
            z += (edge[i] == 0) ? 1 : 0;
        }
        for (int s = 32; s; s >>= 1) z += __shfl_down(z, s);
        if (lane == 0) flags[1] = (z > 64) ? 1 : 0;
    } else {
        int z = 0;
#pragma unroll
        for (int r = 0; r < 2; r++) {
            int i = 1025 + 2 * lane + 128 * r;     // odd indices 1025..1279
            z += (batch[i] == 0) ? 1 : 0;
        }
        for (int s = 32; s; s >>= 1) z += __shfl_down(z, s);
        if (lane == 0) flags[2] = (z > 64) ? 1 : 0;
    }
}

// ---------------- conv: weights -> bf16 (transposed for GEMMs), grid-stride ----------------
__global__ __launch_bounds__(256) void k_prep_conv(const void* __restrict__ W1,
                                                   const void* __restrict__ b1,
                                                   const void* __restrict__ W2,
                                                   const void* __restrict__ b2,
                                                   const void* __restrict__ Wfc,
                                                   const void* __restrict__ bfc,
                                                   const int* __restrict__ flags,
                                                   bf16* __restrict__ W1t, bf16* __restrict__ W2t,
                                                   bf16* __restrict__ b1c, bf16* __restrict__ b2c,
                                                   bf16* __restrict__ Wfcc, bf16* __restrict__ bfcc) {
    int f0 = flags[0];
    int gid = blockIdx.x * 256 + threadIdx.x;
    int stride = gridDim.x * 256;
#define CV(src, si) (f0 ? __float2bfloat16(((const float*)(src))[si]) : ((const bf16*)(src))[si])
    for (int i = gid; i < FDIM * HDIM; i += stride) {       // W1t[n*64+k] = W1[k*128+n]
        int n = i >> 6, k = i & 63;
        W1t[i] = CV(W1, k * HDIM + n);
    }
    for (int i = gid; i < HDIM * HDIM; i += stride) {       // W2t[n*128+k] = W2[k*128+n]
        int n = i >> 7, k = i & 127;
        W2t[i] = CV(W2, k * HDIM + n);
    }
    for (int i = gid; i < HDIM; i += stride) b1c[i] = CV(b1, i);
    for (int i = gid; i < HDIM; i += stride) b2c[i] = CV(b2, i);
    for (int i = gid; i < HDIM * 2; i += stride) Wfcc[i] = CV(Wfc, i);
    for (int i = gid; i < 2; i += stride) bfcc[i] = CV(bfc, i);
#undef CV
}

__device__ __forceinline__ int edge_word(const int* e, long long logical_idx, int is64) {
    return is64 ? e[2 * logical_idx] : e[logical_idx];
}

// ---------------- CSR build ----------------
__global__ void k_count(const int* __restrict__ edge, int* __restrict__ count, int E,
                        const int* __restrict__ flags) {
    int i = blockIdx.x * blockDim.x + threadIdx.x;
    if (i >= E) return;
    int d = edge_word(edge, (long long)E + i, flags[1]);
    atomicAdd(&count[d], 1);
}

__global__ __launch_bounds__(256) void k_scan_partial(const int* __restrict__ count,
                                                      int* __restrict__ parts, int N) {
    __shared__ int red[256];
    int base = blockIdx.x * SCHUNK;
    int t = threadIdx.x;
    int i0 = base + 2 * t, i1 = base + 2 * t + 1;
    int v = 0;
    if (i0 < N) v += count[i0];
    if (i1 < N) v += count[i1];
    red[t] = v;
    __syncthreads();
    for (int s = 128; s > 0; s >>= 1) {
        if (t < s) red[t] += red[t + s];
        __syncthreads();
    }
    if (t == 0) parts[blockIdx.x] = red[0];
}

__global__ __launch_bounds__(256) void k_scan_parts(const int* __restrict__ parts,
                                                    int* __restrict__ partsx, int NP) {
    __shared__ int a[256], b[256];
    int t = threadIdx.x;
    int own = (t < NP) ? parts[t] : 0;
    a[t] = own;
    __syncthreads();
    int* cur = a; int* nxt = b;
    for (int off = 1; off < 256; off <<= 1) {
        int v = cur[t];
        if (t >= off) v += cur[t - off];
        nxt[t] = v;
        __syncthreads();
        int* tmp = cur; cur = nxt; nxt = tmp;
    }
    if (t < NP) partsx[t] = cur[t] - own;
}

__global__ __launch_bounds__(512) void k_scan_final(const int* __restrict__ count,
                                                    const int* __restrict__ partsx,
                                                    int* __restrict__ rowptr,
                                                    float* __restrict__ dinv, int N) {
    __shared__ int a[512], b[512];
    int t = threadIdx.x;
    int idx = blockIdx.x * SCHUNK + t;
    int own = (idx < N) ? count[idx] : 0;
    a[t] = own;
    __syncthreads();
    int* cur = a; int* nxt = b;
    for (int off = 1; off < 512; off <<= 1) {
        int v = cur[t];
        if (t >= off) v += cur[t - off];
        nxt[t] = v;
        __syncthreads();
        int* tmp = cur; cur = nxt; nxt = tmp;
    }
    if (idx < N) {
        rowptr[idx] = cur[t] - own + partsx[blockIdx.x];
        dinv[idx] = rsqrtf((float)own + 1.0f);
    }
}

__global__ void k_fill(const int* __restrict__ edge, const int* __restrict__ rowptr,
                       int* __restrict__ cursor, int* __restrict__ srclist, int E,
                       const int* __restrict__ flags) {
    int i = blockIdx.x * blockDim.x + threadIdx.x;
    if (i >= E) return;
    int is64 = flags[1];
    int s = edge_word(edge, i, is64);
    int d = edge_word(edge, (long long)E + i, is64);
    int pos = rowptr[d] + atomicAdd(&cursor[d], 1);
    srclist[pos] = s;
}

// ---------------- MFMA GEMM1 ----------------
#define K1PAD 72
__global__ __launch_bounds__(256) void k_gemm1(const void* __restrict__ x,
                                               const bf16* __restrict__ W1t,
                                               bf16* __restrict__ h1, int N,
                                               const int* __restrict__ flags) {
    __shared__ bf16 As[64 * K1PAD];
    __shared__ bf16 Wt[HDIM * K1PAD];
    int tid = threadIdx.x;
    int base = blockIdx.x * 64;
    {
        const uint4* wsrc = (const uint4*)W1t;
        for (int i = tid; i < HDIM * 8; i += 256) {
            int n = i >> 3, c = i & 7;
            *(uint4*)&Wt[n * K1PAD + c * 8] = wsrc[n * 8 + c];
        }
    }
    if (flags[0]) {
        const float4* xf = (const float4*)x;
        for (int i = tid; i < 64 * 16; i += 256) {
            int r = i >> 4, c = i & 15;
            int gr = base + r; if (gr >= N) gr = N - 1;
            float4 v = xf[(size_t)gr * 16 + c];
            unsigned int p0 = ((unsigned int)f2bits(v.y) << 16) | f2bits(v.x);
            unsigned int p1 = ((unsigned int)f2bits(v.w) << 16) | f2bits(v.z);
            *(uint2*)&As[r * K1PAD + c * 4] = make_uint2(p0, p1);
        }
    } else {
        const uint4* xb = (const uint4*)x;
        for (int i = tid; i < 64 * 8; i += 256) {
            int r = i >> 3, c = i & 7;
            int gr = base + r; if (gr >= N) gr = N - 1;
            *(uint4*)&As[r * K1PAD + c * 8] = xb[(size_t)gr * 8 + c];
        }
    }
    __syncthreads();
    int wid = tid >> 6, lane = tid & 63;
    int l15 = lane & 15, q = lane >> 4;
    int m0 = wid * 16;
    short8 af[2];
#pragma unroll
    for (int kc = 0; kc < 2; kc++)
        af[kc] = *(const short8*)&As[(m0 + l15) * K1PAD + kc * 32 + q * 8];
    f32x4 acc[8];
#pragma unroll
    for (int nt = 0; nt < 8; nt++) {
        acc[nt] = (f32x4){0.f, 0.f, 0.f, 0.f};
#pragma unroll
        for (int kc = 0; kc < 2; kc++) {
            short8 bf = *(const short8*)&Wt[(nt * 16 + l15) * K1PAD + kc * 32 + q * 8];
            acc[nt] = __builtin_amdgcn_mfma_f32_16x16x32_bf16(af[kc], bf, acc[nt], 0, 0, 0);
        }
    }
#pragma unroll
    for (int nt = 0; nt < 8; nt++) {
        int col = nt * 16 + l15;
#pragma unroll
        for (int r = 0; r < 4; r++) {
            int gr = base + m0 + q * 4 + r;
            if (gr < N) h1[(size_t)gr * HDIM + col] = __float2bfloat16(acc[nt][r]);
        }
    }
}

// ---------------- MFMA GEMM2 ----------------
#define K2PAD 136
__global__ __launch_bounds__(256) void k_gemm2(const bf16* __restrict__ xin,
                                               const bf16* __restrict__ W2t,
                                               bf16* __restrict__ outp, int N) {
    __shared__ bf16 As[64 * K2PAD];
    __shared__ bf16 Wt[HDIM * K2PAD];
    int tid = threadIdx.x;
    int base = blockIdx.x * 64;
    {
        const uint4* wsrc = (const uint4*)W2t;
        for (int i = tid; i < HDIM * 16; i += 256) {
            int n = i >> 4, c = i & 15;
            *(uint4*)&Wt[n * K2PAD + c * 8] = wsrc[n * 16 + c];
        }
    }
    const uint4* xb = (const uint4*)xin;
    for (int i = tid; i < 64 * 16; i += 256) {
        int r = i >> 4, c = i & 15;
        int gr = base + r; if (gr >= N) gr = N - 1;
        *(uint4*)&As[r * K2PAD + c * 8] = xb[(size_t)gr * 16 + c];
    }
    __syncthreads();
    int wid = tid >> 6, lane = tid & 63;
    int l15 = lane & 15, q = lane >> 4;
    int m0 = wid * 16;
    short8 af[4];
#pragma unroll
    for (int kc = 0; kc < 4; kc++)
        af[kc] = *(const short8*)&As[(m0 + l15) * K2PAD + kc * 32 + q * 8];
    f32x4 acc[8];
#pragma unroll
    for (int nt = 0; nt < 8; nt++) {
        acc[nt] = (f32x4){0.f, 0.f, 0.f, 0.f};
#pragma unroll
        for (int kc = 0; kc < 4; kc++) {
            short8 bf = *(const short8*)&Wt[(nt * 16 + l15) * K2PAD + kc * 32 + q * 8];
            acc[nt] = __builtin_amdgcn_mfma_f32_16x16x32_bf16(af[kc], bf, acc[nt], 0, 0, 0);
        }
    }
#pragma unroll
    for (int nt = 0; nt < 8; nt++) {
        int col = nt * 16 + l15;
#pragma unroll
        for (int r = 0; r < 4; r++) {
            int gr = base + m0 + q * 4 + r;
            if (gr < N) outp[(size_t)gr * HDIM + col] = __float2bfloat16(acc[nt][r]);
        }
    }
}

// ---------------- aggregate (shfl-batched neighbor prefetch) ----------------
__global__ __launch_bounds__(256) void k_aggregate(const bf16* __restrict__ h,
                                                   const int* __restrict__ srclist,
                                                   const int* __restrict__ rowptr,
                                                   const int* __restrict__ count,
                                                   const float* __restrict__ dinv,
                                                   const bf16* __restrict__ bias,
                                                   bf16* __restrict__ outb, int N) {
    int wid = threadIdx.x >> 6;
    int lane = threadIdx.x & 63;
    int i = blockIdx.x * 4 + wid;
    if (i >= N) return;
    int start = rowptr[i];
    int cnt = count[i];
    float di = dinv[i];
    const unsigned int* hrow = (const unsigned int*)h;
    float a0 = 0.f, a1 = 0.f, p0 = 0.f, p1 = 0.f, q0 = 0.f, q1 = 0.f, r0a = 0.f, r1a = 0.f;
    for (int bj = 0; bj < cnt; bj += 64) {
        int m = cnt - bj; if (m > 64) m = 64;
        int idx = bj + ((lane < m) ? lane : (m - 1));
        int sv = srclist[start + idx];
        float dvv = dinv[sv];
        int j = 0;
        for (; j + 4 <= m; j += 4) {
            int s0 = __shfl(sv, j), s1 = __shfl(sv, j + 1);
            int s2 = __shfl(sv, j + 2), s3 = __shfl(sv, j + 3);
            float e0 = __shfl(dvv, j), e1 = __shfl(dvv, j + 1);
            float e2 = __shfl(dvv, j + 2), e3 = __shfl(dvv, j + 3);
            unsigned int v0 = hrow[(size_t)s0 * 64 + lane];
            unsigned int v1 = hrow[(size_t)s1 * 64 + lane];
            unsigned int v2 = hrow[(size_t)s2 * 64 + lane];
            unsigned int v3 = hrow[(size_t)s3 * 64 + lane];
            a0 += bits2f(v0 & 0xFFFFu) * e0; a1 += bits2f(v0 >> 16) * e0;
            p0 += bits2f(v1 & 0xFFFFu) * e1; p1 += bits2f(v1 >> 16) * e1;
            q0 += bits2f(v2 & 0xFFFFu) * e2; q1 += bits2f(v2 >> 16) * e2;
            r0a += bits2f(v3 & 0xFFFFu) * e3; r1a += bits2f(v3 >> 16) * e3;
        }
        for (; j < m; j++) {
            int s0 = __shfl(sv, j);
            float e0 = __shfl(dvv, j);
            unsigned int v0 = hrow[(size_t)s0 * 64 + lane];
            a0 += bits2f(v0 & 0xFFFFu) * e0; a1 += bits2f(v0 >> 16) * e0;
        }
    }
    a0 = (a0 + p0) + (q0 + r0a);
    a1 = (a1 + p1) + (q1 + r1a);
    unsigned int vs = hrow[(size_t)i * 64 + lane];
    float self = di * di;
    float b0 = b2f(bias[2 * lane]);
    float b1 = b2f(bias[2 * lane + 1]);
    float o0 = fmaxf(di * a0 + bits2f(vs & 0xFFFFu) * self + b0, 0.f);
    float o1 = fmaxf(di * a1 + bits2f(vs >> 16) * self + b1, 0.f);
    unsigned int packed = ((unsigned int)f2bits(o1) << 16) | f2bits(o0);
    ((unsigned int*)outb)[(size_t)i * 64 + lane] = packed;
}

// ---------------- pool phase A: streaming per-graph sums ----------------
// 4 waves/block; wave w handles rows base+w+4k; lane holds col-pair (uint).
// batch sorted -> run-length accumulate in regs, atomic flush on boundary.
__global__ __launch_bounds__(256) void k_pool_sum(const bf16* __restrict__ hact,
                                                  const int* __restrict__ batch,
                                                  float* __restrict__ Gsum,
                                                  float* __restrict__ Gcnt,
                                                  int N, const int* __restrict__ flags) {
    int wave = threadIdx.x >> 6, lane = threadIdx.x & 63;
    int base = blockIdx.x * PROWS;
    int is64 = flags[2];
    const unsigned int* hrow = (const unsigned int*)hact;
    float a0 = 0.f, a1 = 0.f;
    int c = 0, gcur = -1;
    for (int k = 0; k < PROWS / 4; k++) {
        int r = base + wave + 4 * k;
        if (r >= N) break;
        int g = is64 ? batch[2 * r] : batch[r];
        if (g != gcur) {
            if (gcur >= 0) {
                atomicAdd(&Gsum[gcur * HDIM + 2 * lane], a0);
                atomicAdd(&Gsum[gcur * HDIM + 2 * lane + 1], a1);
                if (lane == 0) atomicAdd(&Gcnt[gcur], (float)c);
            }
            a0 = a1 = 0.f; c = 0; gcur = g;
        }
        unsigned int v = hrow[(size_t)r * 64 + lane];
        a0 += bits2f(v & 0xFFFFu);
        a1 += bits2f(v >> 16);
        c++;
    }
    if (gcur >= 0) {
        atomicAdd(&Gsum[gcur * HDIM + 2 * lane], a0);
        atomicAdd(&Gsum[gcur * HDIM + 2 * lane + 1], a1);
        if (lane == 0) atomicAdd(&Gcnt[gcur], (float)c);
    }
}

// ---------------- pool phase B: mean + FC + softmax (wave per graph) ----------------
__global__ __launch_bounds__(256) void k_pool_fc(const float* __restrict__ Gsum,
                                                 const float* __restrict__ Gcnt,
                                                 const bf16* __restrict__ Wfc,
                                                 const bf16* __restrict__ bfc,
                                                 void* __restrict__ out, int G,
                                                 const int* __restrict__ flags) {
    int wave = threadIdx.x >> 6, lane = threadIdx.x & 63;
    int g = blockIdx.x * 4 + wave;
    if (g >= G) return;
    float inv = 1.0f / fmaxf(Gcnt[g], 1.0f);
    float m0 = Gsum[g * HDIM + 2 * lane] * inv;
    float m1 = Gsum[g * HDIM + 2 * lane + 1] * inv;
    float l0 = m0 * b2f(Wfc[(2 * lane) * 2 + 0]) + m1 * b2f(Wfc[(2 * lane + 1) * 2 + 0]);
    float l1 = m0 * b2f(Wfc[(2 * lane) * 2 + 1]) + m1 * b2f(Wfc[(2 * lane + 1) * 2 + 1]);
    for (int s = 32; s; s >>= 1) { l0 += __shfl_down(l0, s); l1 += __shfl_down(l1, s); }
    if (lane == 0) {
        float z0 = l0 + b2f(bfc[0]);
        float z1 = l1 + b2f(bfc[1]);
        float mx = fmaxf(z0, z1);
        float e0 = expf(z0 - mx), e1 = expf(z1 - mx);
        float s = e0 + e1;
        float p0 = e0 / s, p1 = e1 / s;
        if (flags[0]) {
            ((float*)out)[2 * g + 0] = p0;
            ((float*)out)[2 * g + 1] = p1;
        } else {
            ((bf16*)out)[2 * g + 0] = __float2bfloat16(p0);
            ((bf16*)out)[2 * g + 1] = __float2bfloat16(p1);
        }
    }
}

extern "C" void kernel_launch(void* const* d_in, const int* in_sizes, int n_in,
                              void* d_out, int out_size, void* d_ws, size_t ws_size,
                              hipStream_t stream) {
    const void* x    = d_in[0];
    const int*  edge = (const int*)d_in[1];
    const int*  batch= (const int*)d_in[2];
    const void* W1  = d_in[4];
    const void* b1  = d_in[5];
    const void* W2  = d_in[6];
    const void* b2  = d_in[7];
    const void* Wfc = d_in[8];
    const void* bfc = d_in[9];

    int N = in_sizes[0] / FDIM;   // 100000
    int E = in_sizes[1] / 2;      // 1000000
    int G = out_size / 2;         // 512
    int NP = (N + SCHUNK - 1) / SCHUNK;

    // ws layout. count,cursor,Gsum,Gcnt are contiguous: zeroed by one memset.
    int*   flags  = (int*)d_ws;                          // 64 B
    float* dinv   = (float*)((char*)d_ws + 64);          // N floats
    int*   count  = (int*)(dinv + N);                    // N ints (memset group start)
    int*   cursor = count + N;                           // N ints
    float* Gsum   = (float*)(cursor + N);                // G*128 floats
    float* Gcnt   = Gsum + (size_t)G * HDIM;             // G floats (memset group end)
    int*   rowptr = (int*)(Gcnt + G);                    // N ints
    int*   parts  = rowptr + N;                          // 256
    int*   partsx = parts + 256;                         // 256
    int*   srclist= partsx + 256;                        // E
    bf16*  Hbuf   = (bf16*)(srclist + E);                // N*128
    bf16*  Bbuf   = Hbuf + (size_t)N * HDIM;             // N*128
    bf16*  b1c    = Bbuf + (size_t)N * HDIM;             // 128
    bf16*  b2c    = b1c + HDIM;                          // 128
    bf16*  Wfcc   = b2c + HDIM;                          // 256
    bf16*  bfcc   = Wfcc + 256;                          // 64 (pad)
    bf16*  W1t    = bfcc + 64;                           // 8192
    bf16*  W2t    = W1t + FDIM * HDIM;                   // 16384

    k_prep_flags<<<1, 192, 0, stream>>>((const unsigned short*)W1, edge, batch, flags);
    k_prep_conv<<<32, 256, 0, stream>>>(W1, b1, W2, b2, Wfc, bfc, flags,
                                        W1t, W2t, b1c, b2c, Wfcc, bfcc);

    hipMemsetAsync(count, 0, ((size_t)2 * N + (size_t)G * HDIM + G) * sizeof(int), stream);
    k_count<<<(E + 255) / 256, 256, 0, stream>>>(edge, count, E, flags);
    k_scan_partial<<<NP, 256, 0, stream>>>(count, parts, N);
    k_scan_parts<<<1, 256, 0, stream>>>(parts, partsx, NP);
    k_scan_final<<<NP, 512, 0, stream>>>(count, partsx, rowptr, dinv, N);
    k_fill<<<(E + 255) / 256, 256, 0, stream>>>(edge, rowptr, cursor, srclist, E, flags);

    // layer 1
    k_gemm1<<<(N + 63) / 64, 256, 0, stream>>>(x, W1t, Hbuf, N, flags);
    k_aggregate<<<(N + 3) / 4, 256, 0, stream>>>(Hbuf, srclist, rowptr, count, dinv, b1c, Bbuf, N);

    // layer 2
    k_gemm2<<<(N + 63) / 64, 256, 0, stream>>>(Bbuf, W2t, Hbuf, N);
    k_aggregate<<<(N + 3) / 4, 256, 0, stream>>>(Hbuf, srclist, rowptr, count, dinv, b2c, Bbuf, N);

    // pool + fc + softmax
    k_pool_sum<<<(N + PROWS - 1) / PROWS, 256, 0, stream>>>(Bbuf, batch, Gsum, Gcnt, N, flags);
    k_pool_fc<<<(G + 3) / 4, 256, 0, stream>>>(Gsum, Gcnt, Wfcc, bfcc, d_out, G, flags);
}

// Round 9
// 343.468 us; speedup vs baseline: 21.5164x; 1.1543x over previous
//
#include <hip/hip_runtime.h>
#include <hip/hip_bf16.h>

typedef __hip_bfloat16 bf16;
typedef __attribute__((ext_vector_type(8))) short short8;
typedef __attribute__((ext_vector_type(4))) float f32x4;

#define FDIM 64
#define HDIM 128
#define SCHUNK 512
#define PROWS 256

__device__ __forceinline__ float b2f(bf16 v) { return __bfloat162float(v); }
__device__ __forceinline__ float bits2f(unsigned int u) {
    return __uint_as_float(u << 16);
}
__device__ __forceinline__ unsigned short f2bits(float f) {
    bf16 b = __float2bfloat16(f);
    return *reinterpret_cast<unsigned short*>(&b);
}

// ---------------- flags: parallel dtype detection (1 block, 3 waves) ----------------
__global__ __launch_bounds__(192) void k_prep_flags(const unsigned short* __restrict__ w1u,
                                                    const int* __restrict__ edge,
                                                    const int* __restrict__ batch,
                                                    int* __restrict__ flags) {
    int wave = threadIdx.x >> 6, lane = threadIdx.x & 63;
    if (wave == 0) {
        int wild = 0;
#pragma unroll
        for (int r = 0; r < 2; r++) {
            int i = 2 * lane + 128 * r;            // even indices 0..254
            int e = (w1u[i] >> 7) & 0xFF;
            wild += (e == 0 || e >= 137) ? 1 : 0;
        }
        for (int s = 32; s; s >>= 1) wild += __shfl_down(wild, s);
        if (lane == 0) flags[0] = (wild > 16) ? 1 : 0;
    } else if (wave == 1) {
        int z = 0;
#pragma unroll
        for (int r = 0; r < 2; r++) {
            int i = 2 * lane + 1 + 128 * r;        // odd indices 1..255
            z += (edge[i] == 0) ? 1 : 0;
        }
        for (int s = 32; s; s >>= 1) z += __shfl_down(z, s);
        if (lane == 0) flags[1] = (z > 64) ? 1 : 0;
    } else {
        int z = 0;
#pragma unroll
        for (int r = 0; r < 2; r++) {
            int i = 1025 + 2 * lane + 128 * r;     // odd indices 1025..1279
            z += (batch[i] == 0) ? 1 : 0;
        }
        for (int s = 32; s; s >>= 1) z += __shfl_down(z, s);
        if (lane == 0) flags[2] = (z > 64) ? 1 : 0;
    }
}

// ---------------- conv: weights -> bf16 (transposed for GEMMs), grid-stride ----------------
__global__ __launch_bounds__(256) void k_prep_conv(const void* __restrict__ W1,
                                                   const void* __restrict__ b1,
                                                   const void* __restrict__ W2,
                                                   const void* __restrict__ b2,
                                                   const void* __restrict__ Wfc,
                                                   const void* __restrict__ bfc,
                                                   const int* __restrict__ flags,
                                                   bf16* __restrict__ W1t, bf16* __restrict__ W2t,
                                                   bf16* __restrict__ b1c, bf16* __restrict__ b2c,
                                                   bf16* __restrict__ Wfcc, bf16* __restrict__ bfcc) {
    int f0 = flags[0];
    int gid = blockIdx.x * 256 + threadIdx.x;
    int stride = gridDim.x * 256;
#define CV(src, si) (f0 ? __float2bfloat16(((const float*)(src))[si]) : ((const bf16*)(src))[si])
    for (int i = gid; i < FDIM * HDIM; i += stride) {       // W1t[n*64+k] = W1[k*128+n]
        int n = i >> 6, k = i & 63;
        W1t[i] = CV(W1, k * HDIM + n);
    }
    for (int i = gid; i < HDIM * HDIM; i += stride) {       // W2t[n*128+k] = W2[k*128+n]
        int n = i >> 7, k = i & 127;
        W2t[i] = CV(W2, k * HDIM + n);
    }
    for (int i = gid; i < HDIM; i += stride) b1c[i] = CV(b1, i);
    for (int i = gid; i < HDIM; i += stride) b2c[i] = CV(b2, i);
    for (int i = gid; i < HDIM * 2; i += stride) Wfcc[i] = CV(Wfc, i);
    for (int i = gid; i < 2; i += stride) bfcc[i] = CV(bfc, i);
#undef CV
}

__device__ __forceinline__ int edge_word(const int* e, long long logical_idx, int is64) {
    return is64 ? e[2 * logical_idx] : e[logical_idx];
}

// ---------------- CSR build ----------------
// count + per-edge rank (atomic return value; order within dst irrelevant for sum)
__global__ void k_count(const int* __restrict__ edge, int* __restrict__ count,
                        int* __restrict__ rank, int E, const int* __restrict__ flags) {
    int i = blockIdx.x * blockDim.x + threadIdx.x;
    if (i >= E) return;
    int d = edge_word(edge, (long long)E + i, flags[1]);
    rank[i] = atomicAdd(&count[d], 1);
}

__global__ __launch_bounds__(256) void k_scan_partial(const int* __restrict__ count,
                                                      int* __restrict__ parts, int N) {
    __shared__ int red[256];
    int base = blockIdx.x * SCHUNK;
    int t = threadIdx.x;
    int i0 = base + 2 * t, i1 = base + 2 * t + 1;
    int v = 0;
    if (i0 < N) v += count[i0];
    if (i1 < N) v += count[i1];
    red[t] = v;
    __syncthreads();
    for (int s = 128; s > 0; s >>= 1) {
        if (t < s) red[t] += red[t + s];
        __syncthreads();
    }
    if (t == 0) parts[blockIdx.x] = red[0];
}

__global__ __launch_bounds__(256) void k_scan_parts(const int* __restrict__ parts,
                                                    int* __restrict__ partsx, int NP) {
    __shared__ int a[256], b[256];
    int t = threadIdx.x;
    int own = (t < NP) ? parts[t] : 0;
    a[t] = own;
    __syncthreads();
    int* cur = a; int* nxt = b;
    for (int off = 1; off < 256; off <<= 1) {
        int v = cur[t];
        if (t >= off) v += cur[t - off];
        nxt[t] = v;
        __syncthreads();
        int* tmp = cur; cur = nxt; nxt = tmp;
    }
    if (t < NP) partsx[t] = cur[t] - own;
}

__global__ __launch_bounds__(512) void k_scan_final(const int* __restrict__ count,
                                                    const int* __restrict__ partsx,
                                                    int* __restrict__ rowptr,
                                                    float* __restrict__ dinv, int N) {
    __shared__ int a[512], b[512];
    int t = threadIdx.x;
    int idx = blockIdx.x * SCHUNK + t;
    int own = (idx < N) ? count[idx] : 0;
    a[t] = own;
    __syncthreads();
    int* cur = a; int* nxt = b;
    for (int off = 1; off < 512; off <<= 1) {
        int v = cur[t];
        if (t >= off) v += cur[t - off];
        nxt[t] = v;
        __syncthreads();
        int* tmp = cur; cur = nxt; nxt = tmp;
    }
    if (idx < N) {
        rowptr[idx] = cur[t] - own + partsx[blockIdx.x];
        dinv[idx] = rsqrtf((float)own + 1.0f);
    }
}

// atomic-free fill: position = rowptr[dst] + precomputed rank
__global__ void k_fill(const int* __restrict__ edge, const int* __restrict__ rowptr,
                       const int* __restrict__ rank, int* __restrict__ srclist, int E,
                       const int* __restrict__ flags) {
    int i = blockIdx.x * blockDim.x + threadIdx.x;
    if (i >= E) return;
    int is64 = flags[1];
    int s = edge_word(edge, i, is64);
    int d = edge_word(edge, (long long)E + i, is64);
    srclist[rowptr[d] + rank[i]] = s;
}

// ---------------- MFMA GEMM1 ----------------
#define K1PAD 72
__global__ __launch_bounds__(256) void k_gemm1(const void* __restrict__ x,
                                               const bf16* __restrict__ W1t,
                                               bf16* __restrict__ h1, int N,
                                               const int* __restrict__ flags) {
    __shared__ bf16 As[64 * K1PAD];
    __shared__ bf16 Wt[HDIM * K1PAD];
    int tid = threadIdx.x;
    int base = blockIdx.x * 64;
    {
        const uint4* wsrc = (const uint4*)W1t;
        for (int i = tid; i < HDIM * 8; i += 256) {
            int n = i >> 3, c = i & 7;
            *(uint4*)&Wt[n * K1PAD + c * 8] = wsrc[n * 8 + c];
        }
    }
    if (flags[0]) {
        const float4* xf = (const float4*)x;
        for (int i = tid; i < 64 * 16; i += 256) {
            int r = i >> 4, c = i & 15;
            int gr = base + r; if (gr >= N) gr = N - 1;
            float4 v = xf[(size_t)gr * 16 + c];
            unsigned int p0 = ((unsigned int)f2bits(v.y) << 16) | f2bits(v.x);
            unsigned int p1 = ((unsigned int)f2bits(v.w) << 16) | f2bits(v.z);
            *(uint2*)&As[r * K1PAD + c * 4] = make_uint2(p0, p1);
        }
    } else {
        const uint4* xb = (const uint4*)x;
        for (int i = tid; i < 64 * 8; i += 256) {
            int r = i >> 3, c = i & 7;
            int gr = base + r; if (gr >= N) gr = N - 1;
            *(uint4*)&As[r * K1PAD + c * 8] = xb[(size_t)gr * 8 + c];
        }
    }
    __syncthreads();
    int wid = tid >> 6, lane = tid & 63;
    int l15 = lane & 15, q = lane >> 4;
    int m0 = wid * 16;
    short8 af[2];
#pragma unroll
    for (int kc = 0; kc < 2; kc++)
        af[kc] = *(const short8*)&As[(m0 + l15) * K1PAD + kc * 32 + q * 8];
    f32x4 acc[8];
#pragma unroll
    for (int nt = 0; nt < 8; nt++) {
        acc[nt] = (f32x4){0.f, 0.f, 0.f, 0.f};
#pragma unroll
        for (int kc = 0; kc < 2; kc++) {
            short8 bf = *(const short8*)&Wt[(nt * 16 + l15) * K1PAD + kc * 32 + q * 8];
            acc[nt] = __builtin_amdgcn_mfma_f32_16x16x32_bf16(af[kc], bf, acc[nt], 0, 0, 0);
        }
    }
#pragma unroll
    for (int nt = 0; nt < 8; nt++) {
        int col = nt * 16 + l15;
#pragma unroll
        for (int r = 0; r < 4; r++) {
            int gr = base + m0 + q * 4 + r;
            if (gr < N) h1[(size_t)gr * HDIM + col] = __float2bfloat16(acc[nt][r]);
        }
    }
}

// ---------------- MFMA GEMM2 ----------------
#define K2PAD 136
__global__ __launch_bounds__(256) void k_gemm2(const bf16* __restrict__ xin,
                                               const bf16* __restrict__ W2t,
                                               bf16* __restrict__ outp, int N) {
    __shared__ bf16 As[64 * K2PAD];
    __shared__ bf16 Wt[HDIM * K2PAD];
    int tid = threadIdx.x;
    int base = blockIdx.x * 64;
    {
        const uint4* wsrc = (const uint4*)W2t;
        for (int i = tid; i < HDIM * 16; i += 256) {
            int n = i >> 4, c = i & 15;
            *(uint4*)&Wt[n * K2PAD + c * 8] = wsrc[n * 16 + c];
        }
    }
    const uint4* xb = (const uint4*)xin;
    for (int i = tid; i < 64 * 16; i += 256) {
        int r = i >> 4, c = i & 15;
        int gr = base + r; if (gr >= N) gr = N - 1;
        *(uint4*)&As[r * K2PAD + c * 8] = xb[(size_t)gr * 16 + c];
    }
    __syncthreads();
    int wid = tid >> 6, lane = tid & 63;
    int l15 = lane & 15, q = lane >> 4;
    int m0 = wid * 16;
    short8 af[4];
#pragma unroll
    for (int kc = 0; kc < 4; kc++)
        af[kc] = *(const short8*)&As[(m0 + l15) * K2PAD + kc * 32 + q * 8];
    f32x4 acc[8];
#pragma unroll
    for (int nt = 0; nt < 8; nt++) {
        acc[nt] = (f32x4){0.f, 0.f, 0.f, 0.f};
#pragma unroll
        for (int kc = 0; kc < 4; kc++) {
            short8 bf = *(const short8*)&Wt[(nt * 16 + l15) * K2PAD + kc * 32 + q * 8];
            acc[nt] = __builtin_amdgcn_mfma_f32_16x16x32_bf16(af[kc], bf, acc[nt], 0, 0, 0);
        }
    }
#pragma unroll
    for (int nt = 0; nt < 8; nt++) {
        int col = nt * 16 + l15;
#pragma unroll
        for (int r = 0; r < 4; r++) {
            int gr = base + m0 + q * 4 + r;
            if (gr < N) outp[(size_t)gr * HDIM + col] = __float2bfloat16(acc[nt][r]);
        }
    }
}

// ---------------- aggregate: 16 lanes per node (uint4/row-chunk), 4 nodes/wave ----------------
// Each 16-lane group handles one node; lane loads 16B (8 bf16 feats) of each
// neighbor row -> 4x unroll gives 16 outstanding 16B gathers per wave.
#define ACC8(v, e) do { \
    acc[0] += bits2f((v).x & 0xFFFFu) * (e); acc[1] += bits2f((v).x >> 16) * (e); \
    acc[2] += bits2f((v).y & 0xFFFFu) * (e); acc[3] += bits2f((v).y >> 16) * (e); \
    acc[4] += bits2f((v).z & 0xFFFFu) * (e); acc[5] += bits2f((v).z >> 16) * (e); \
    acc[6] += bits2f((v).w & 0xFFFFu) * (e); acc[7] += bits2f((v).w >> 16) * (e); } while (0)

__global__ __launch_bounds__(256) void k_aggregate(const bf16* __restrict__ h,
                                                   const int* __restrict__ srclist,
                                                   const int* __restrict__ rowptr,
                                                   const int* __restrict__ count,
                                                   const float* __restrict__ dinv,
                                                   const bf16* __restrict__ bias,
                                                   bf16* __restrict__ outb, int N) {
    int wave = threadIdx.x >> 6;
    int lane = threadIdx.x & 63;
    int group = lane >> 4;
    int sub = lane & 15;
    int i = blockIdx.x * 16 + wave * 4 + group;
    if (i >= N) return;
    int start = rowptr[i];
    int cnt = count[i];
    float di = dinv[i];
    const uint4* hrow = (const uint4*)h;
    float acc[8] = {0.f, 0.f, 0.f, 0.f, 0.f, 0.f, 0.f, 0.f};
    int lb = group << 4;
    for (int jb = 0; jb < cnt; jb += 16) {
        int m = cnt - jb; if (m > 16) m = 16;
        int sv = srclist[start + jb + ((sub < m) ? sub : (m - 1))];
        float dvv = dinv[sv];
        int j = 0;
        for (; j + 4 <= m; j += 4) {
            int s0 = __shfl(sv, lb + j + 0); float e0 = __shfl(dvv, lb + j + 0);
            int s1 = __shfl(sv, lb + j + 1); float e1 = __shfl(dvv, lb + j + 1);
            int s2 = __shfl(sv, lb + j + 2); float e2 = __shfl(dvv, lb + j + 2);
            int s3 = __shfl(sv, lb + j + 3); float e3 = __shfl(dvv, lb + j + 3);
            uint4 v0 = hrow[(size_t)s0 * 16 + sub];
            uint4 v1 = hrow[(size_t)s1 * 16 + sub];
            uint4 v2 = hrow[(size_t)s2 * 16 + sub];
            uint4 v3 = hrow[(size_t)s3 * 16 + sub];
            ACC8(v0, e0); ACC8(v1, e1); ACC8(v2, e2); ACC8(v3, e3);
        }
        for (; j < m; j++) {
            int s0 = __shfl(sv, lb + j); float e0 = __shfl(dvv, lb + j);
            uint4 v0 = hrow[(size_t)s0 * 16 + sub];
            ACC8(v0, e0);
        }
    }
    uint4 vs = hrow[(size_t)i * 16 + sub];
    uint4 bb = ((const uint4*)bias)[sub];
    float self = di * di;
    float o0 = fmaxf(di * acc[0] + bits2f(vs.x & 0xFFFFu) * self + bits2f(bb.x & 0xFFFFu), 0.f);
    float o1 = fmaxf(di * acc[1] + bits2f(vs.x >> 16) * self + bits2f(bb.x >> 16), 0.f);
    float o2 = fmaxf(di * acc[2] + bits2f(vs.y & 0xFFFFu) * self + bits2f(bb.y & 0xFFFFu), 0.f);
    float o3 = fmaxf(di * acc[3] + bits2f(vs.y >> 16) * self + bits2f(bb.y >> 16), 0.f);
    float o4 = fmaxf(di * acc[4] + bits2f(vs.z & 0xFFFFu) * self + bits2f(bb.z & 0xFFFFu), 0.f);
    float o5 = fmaxf(di * acc[5] + bits2f(vs.z >> 16) * self + bits2f(bb.z >> 16), 0.f);
    float o6 = fmaxf(di * acc[6] + bits2f(vs.w & 0xFFFFu) * self + bits2f(bb.w & 0xFFFFu), 0.f);
    float o7 = fmaxf(di * acc[7] + bits2f(vs.w >> 16) * self + bits2f(bb.w >> 16), 0.f);
    uint4 pv;
    pv.x = ((unsigned int)f2bits(o1) << 16) | f2bits(o0);
    pv.y = ((unsigned int)f2bits(o3) << 16) | f2bits(o2);
    pv.z = ((unsigned int)f2bits(o5) << 16) | f2bits(o4);
    pv.w = ((unsigned int)f2bits(o7) << 16) | f2bits(o6);
    ((uint4*)outb)[(size_t)i * 16 + sub] = pv;
}

// ---------------- pool phase A: streaming per-graph sums ----------------
__global__ __launch_bounds__(256) void k_pool_sum(const bf16* __restrict__ hact,
                                                  const int* __restrict__ batch,
                                                  float* __restrict__ Gsum,
                                                  float* __restrict__ Gcnt,
                                                  int N, const int* __restrict__ flags) {
    int wave = threadIdx.x >> 6, lane = threadIdx.x & 63;
    int base = blockIdx.x * PROWS;
    int is64 = flags[2];
    const unsigned int* hrow = (const unsigned int*)hact;
    float a0 = 0.f, a1 = 0.f;
    int c = 0, gcur = -1;
    for (int k = 0; k < PROWS / 4; k++) {
        int r = base + wave + 4 * k;
        if (r >= N) break;
        int g = is64 ? batch[2 * r] : batch[r];
        if (g != gcur) {
            if (gcur >= 0) {
                atomicAdd(&Gsum[gcur * HDIM + 2 * lane], a0);
                atomicAdd(&Gsum[gcur * HDIM + 2 * lane + 1], a1);
                if (lane == 0) atomicAdd(&Gcnt[gcur], (float)c);
            }
            a0 = a1 = 0.f; c = 0; gcur = g;
        }
        unsigned int v = hrow[(size_t)r * 64 + lane];
        a0 += bits2f(v & 0xFFFFu);
        a1 += bits2f(v >> 16);
        c++;
    }
    if (gcur >= 0) {
        atomicAdd(&Gsum[gcur * HDIM + 2 * lane], a0);
        atomicAdd(&Gsum[gcur * HDIM + 2 * lane + 1], a1);
        if (lane == 0) atomicAdd(&Gcnt[gcur], (float)c);
    }
}

// ---------------- pool phase B: mean + FC + softmax (wave per graph) ----------------
__global__ __launch_bounds__(256) void k_pool_fc(const float* __restrict__ Gsum,
                                                 const float* __restrict__ Gcnt,
                                                 const bf16* __restrict__ Wfc,
                                                 const bf16* __restrict__ bfc,
                                                 void* __restrict__ out, int G,
                                                 const int* __restrict__ flags) {
    int wave = threadIdx.x >> 6, lane = threadIdx.x & 63;
    int g = blockIdx.x * 4 + wave;
    if (g >= G) return;
    float inv = 1.0f / fmaxf(Gcnt[g], 1.0f);
    float m0 = Gsum[g * HDIM + 2 * lane] * inv;
    float m1 = Gsum[g * HDIM + 2 * lane + 1] * inv;
    float l0 = m0 * b2f(Wfc[(2 * lane) * 2 + 0]) + m1 * b2f(Wfc[(2 * lane + 1) * 2 + 0]);
    float l1 = m0 * b2f(Wfc[(2 * lane) * 2 + 1]) + m1 * b2f(Wfc[(2 * lane + 1) * 2 + 1]);
    for (int s = 32; s; s >>= 1) { l0 += __shfl_down(l0, s); l1 += __shfl_down(l1, s); }
    if (lane == 0) {
        float z0 = l0 + b2f(bfc[0]);
        float z1 = l1 + b2f(bfc[1]);
        float mx = fmaxf(z0, z1);
        float e0 = expf(z0 - mx), e1 = expf(z1 - mx);
        float s = e0 + e1;
        float p0 = e0 / s, p1 = e1 / s;
        if (flags[0]) {
            ((float*)out)[2 * g + 0] = p0;
            ((float*)out)[2 * g + 1] = p1;
        } else {
            ((bf16*)out)[2 * g + 0] = __float2bfloat16(p0);
            ((bf16*)out)[2 * g + 1] = __float2bfloat16(p1);
        }
    }
}

extern "C" void kernel_launch(void* const* d_in, const int* in_sizes, int n_in,
                              void* d_out, int out_size, void* d_ws, size_t ws_size,
                              hipStream_t stream) {
    const void* x    = d_in[0];
    const int*  edge = (const int*)d_in[1];
    const int*  batch= (const int*)d_in[2];
    const void* W1  = d_in[4];
    const void* b1  = d_in[5];
    const void* W2  = d_in[6];
    const void* b2  = d_in[7];
    const void* Wfc = d_in[8];
    const void* bfc = d_in[9];

    int N = in_sizes[0] / FDIM;   // 100000
    int E = in_sizes[1] / 2;      // 1000000
    int G = out_size / 2;         // 512
    int NP = (N + SCHUNK - 1) / SCHUNK;

    // ws layout. count,Gsum,Gcnt contiguous: zeroed by one memset.
    int*   flags  = (int*)d_ws;                          // 64 B
    float* dinv   = (float*)((char*)d_ws + 64);          // N floats
    int*   count  = (int*)(dinv + N);                    // N ints (memset group start)
    float* Gsum   = (float*)(count + N);                 // G*128 floats
    float* Gcnt   = Gsum + (size_t)G * HDIM;             // G floats (memset group end)
    int*   rowptr = (int*)(Gcnt + G);                    // N ints
    int*   parts  = rowptr + N;                          // 256
    int*   partsx = parts + 256;                         // 256
    int*   rank   = partsx + 256;                        // E ints
    int*   srclist= rank + E;                            // E ints
    bf16*  Hbuf   = (bf16*)(srclist + E);                // N*128
    bf16*  Bbuf   = Hbuf + (size_t)N * HDIM;             // N*128
    bf16*  b1c    = Bbuf + (size_t)N * HDIM;             // 128
    bf16*  b2c    = b1c + HDIM;                          // 128
    bf16*  Wfcc   = b2c + HDIM;                          // 256
    bf16*  bfcc   = Wfcc + 256;                          // 64 (pad)
    bf16*  W1t    = bfcc + 64;                           // 8192
    bf16*  W2t    = W1t + FDIM * HDIM;                   // 16384

    k_prep_flags<<<1, 192, 0, stream>>>((const unsigned short*)W1, edge, batch, flags);
    k_prep_conv<<<32, 256, 0, stream>>>(W1, b1, W2, b2, Wfc, bfc, flags,
                                        W1t, W2t, b1c, b2c, Wfcc, bfcc);

    hipMemsetAsync(count, 0, ((size_t)N + (size_t)G * HDIM + G) * sizeof(int), stream);
    k_count<<<(E + 255) / 256, 256, 0, stream>>>(edge, count, rank, E, flags);
    k_scan_partial<<<NP, 256, 0, stream>>>(count, parts, N);
    k_scan_parts<<<1, 256, 0, stream>>>(parts, partsx, NP);
    k_scan_final<<<NP, 512, 0, stream>>>(count, partsx, rowptr, dinv, N);
    k_fill<<<(E + 255) / 256, 256, 0, stream>>>(edge, rowptr, rank, srclist, E, flags);

    // layer 1
    k_gemm1<<<(N + 63) / 64, 256, 0, stream>>>(x, W1t, Hbuf, N, flags);
    k_aggregate<<<(N + 15) / 16, 256, 0, stream>>>(Hbuf, srclist, rowptr, count, dinv, b1c, Bbuf, N);

    // layer 2
    k_gemm2<<<(N + 63) / 64, 256, 0, stream>>>(Bbuf, W2t, Hbuf, N);
    k_aggregate<<<(N + 15) / 16, 256, 0, stream>>>(Hbuf, srclist, rowptr, count, dinv, b2c, Bbuf, N);

    // pool + fc + softmax
    k_pool_sum<<<(N + PROWS - 1) / PROWS, 256, 0, stream>>>(Bbuf, batch, Gsum, Gcnt, N, flags);
    k_pool_fc<<<(G + 3) / 4, 256, 0, stream>>>(Gsum, Gcnt, Wfcc, bfcc, d_out, G, flags);
}

// Round 10
// 327.763 us; speedup vs baseline: 22.5474x; 1.0479x over previous
//
#include <hip/hip_runtime.h>
#include <hip/hip_bf16.h>

typedef __hip_bfloat16 bf16;
typedef __attribute__((ext_vector_type(8))) short short8;
typedef __attribute__((ext_vector_type(4))) float f32x4;

#define FDIM 64
#define HDIM 128
#define SCHUNK 512
#define PROWS 256

__device__ __forceinline__ float b2f(bf16 v) { return __bfloat162float(v); }
__device__ __forceinline__ float bits2f(unsigned int u) {
    return __uint_as_float(u << 16);
}
__device__ __forceinline__ unsigned short f2bits(float f) {
    bf16 b = __float2bfloat16(f);
    return *reinterpret_cast<unsigned short*>(&b);
}

// ---------------- flags: parallel dtype detection (1 block, 3 waves) ----------------
__global__ __launch_bounds__(192) void k_prep_flags(const unsigned short* __restrict__ w1u,
                                                    const int* __restrict__ edge,
                                                    const int* __restrict__ batch,
                                                    int* __restrict__ flags) {
    int wave = threadIdx.x >> 6, lane = threadIdx.x & 63;
    if (wave == 0) {
        int wild = 0;
#pragma unroll
        for (int r = 0; r < 2; r++) {
            int i = 2 * lane + 128 * r;
            int e = (w1u[i] >> 7) & 0xFF;
            wild += (e == 0 || e >= 137) ? 1 : 0;
        }
        for (int s = 32; s; s >>= 1) wild += __shfl_down(wild, s);
        if (lane == 0) flags[0] = (wild > 16) ? 1 : 0;
    } else if (wave == 1) {
        int z = 0;
#pragma unroll
        for (int r = 0; r < 2; r++) {
            int i = 2 * lane + 1 + 128 * r;
            z += (edge[i] == 0) ? 1 : 0;
        }
        for (int s = 32; s; s >>= 1) z += __shfl_down(z, s);
        if (lane == 0) flags[1] = (z > 64) ? 1 : 0;
    } else {
        int z = 0;
#pragma unroll
        for (int r = 0; r < 2; r++) {
            int i = 1025 + 2 * lane + 128 * r;
            z += (batch[i] == 0) ? 1 : 0;
        }
        for (int s = 32; s; s >>= 1) z += __shfl_down(z, s);
        if (lane == 0) flags[2] = (z > 64) ? 1 : 0;
    }
}

// ---------------- conv: weights -> bf16 (transposed for GEMMs), grid-stride ----------------
__global__ __launch_bounds__(256) void k_prep_conv(const void* __restrict__ W1,
                                                   const void* __restrict__ b1,
                                                   const void* __restrict__ W2,
                                                   const void* __restrict__ b2,
                                                   const void* __restrict__ Wfc,
                                                   const void* __restrict__ bfc,
                                                   const int* __restrict__ flags,
                                                   bf16* __restrict__ W1t, bf16* __restrict__ W2t,
                                                   bf16* __restrict__ b1c, bf16* __restrict__ b2c,
                                                   bf16* __restrict__ Wfcc, bf16* __restrict__ bfcc) {
    int f0 = flags[0];
    int gid = blockIdx.x * 256 + threadIdx.x;
    int stride = gridDim.x * 256;
#define CV(src, si) (f0 ? __float2bfloat16(((const float*)(src))[si]) : ((const bf16*)(src))[si])
    for (int i = gid; i < FDIM * HDIM; i += stride) {
        int n = i >> 6, k = i & 63;
        W1t[i] = CV(W1, k * HDIM + n);
    }
    for (int i = gid; i < HDIM * HDIM; i += stride) {
        int n = i >> 7, k = i & 127;
        W2t[i] = CV(W2, k * HDIM + n);
    }
    for (int i = gid; i < HDIM; i += stride) b1c[i] = CV(b1, i);
    for (int i = gid; i < HDIM; i += stride) b2c[i] = CV(b2, i);
    for (int i = gid; i < HDIM * 2; i += stride) Wfcc[i] = CV(Wfc, i);
    for (int i = gid; i < 2; i += stride) bfcc[i] = CV(bfc, i);
#undef CV
}

// ---------------- convert X to bf16 (streaming) ----------------
__global__ __launch_bounds__(256) void k_convX(const void* __restrict__ x,
                                               bf16* __restrict__ Xb, int total4,
                                               const int* __restrict__ flags) {
    int t = blockIdx.x * 256 + threadIdx.x;
    if (t >= total4) return;
    if (flags[0]) {
        float4 v = ((const float4*)x)[t];
        uint2 p;
        p.x = ((unsigned int)f2bits(v.y) << 16) | f2bits(v.x);
        p.y = ((unsigned int)f2bits(v.w) << 16) | f2bits(v.z);
        ((uint2*)Xb)[t] = p;
    } else {
        ((uint2*)Xb)[t] = ((const uint2*)x)[t];
    }
}

__device__ __forceinline__ int edge_word(const int* e, long long logical_idx, int is64) {
    return is64 ? e[2 * logical_idx] : e[logical_idx];
}

// ---------------- CSR build ----------------
__global__ void k_count(const int* __restrict__ edge, int* __restrict__ count,
                        int* __restrict__ rank, int E, const int* __restrict__ flags) {
    int i = blockIdx.x * blockDim.x + threadIdx.x;
    if (i >= E) return;
    int d = edge_word(edge, (long long)E + i, flags[1]);
    rank[i] = atomicAdd(&count[d], 1);
}

__global__ __launch_bounds__(256) void k_scan_partial(const int* __restrict__ count,
                                                      int* __restrict__ parts, int N) {
    __shared__ int red[256];
    int base = blockIdx.x * SCHUNK;
    int t = threadIdx.x;
    int i0 = base + 2 * t, i1 = base + 2 * t + 1;
    int v = 0;
    if (i0 < N) v += count[i0];
    if (i1 < N) v += count[i1];
    red[t] = v;
    __syncthreads();
    for (int s = 128; s > 0; s >>= 1) {
        if (t < s) red[t] += red[t + s];
        __syncthreads();
    }
    if (t == 0) parts[blockIdx.x] = red[0];
}

__global__ __launch_bounds__(256) void k_scan_parts(const int* __restrict__ parts,
                                                    int* __restrict__ partsx, int NP) {
    __shared__ int a[256], b[256];
    int t = threadIdx.x;
    int own = (t < NP) ? parts[t] : 0;
    a[t] = own;
    __syncthreads();
    int* cur = a; int* nxt = b;
    for (int off = 1; off < 256; off <<= 1) {
        int v = cur[t];
        if (t >= off) v += cur[t - off];
        nxt[t] = v;
        __syncthreads();
        int* tmp = cur; cur = nxt; nxt = tmp;
    }
    if (t < NP) partsx[t] = cur[t] - own;
}

__global__ __launch_bounds__(512) void k_scan_final(const int* __restrict__ count,
                                                    const int* __restrict__ partsx,
                                                    int* __restrict__ rowptr,
                                                    float* __restrict__ dinv, int N) {
    __shared__ int a[512], b[512];
    int t = threadIdx.x;
    int idx = blockIdx.x * SCHUNK + t;
    int own = (idx < N) ? count[idx] : 0;
    a[t] = own;
    __syncthreads();
    int* cur = a; int* nxt = b;
    for (int off = 1; off < 512; off <<= 1) {
        int v = cur[t];
        if (t >= off) v += cur[t - off];
        nxt[t] = v;
        __syncthreads();
        int* tmp = cur; cur = nxt; nxt = tmp;
    }
    if (idx < N) {
        rowptr[idx] = cur[t] - own + partsx[blockIdx.x];
        dinv[idx] = rsqrtf((float)own + 1.0f);
    }
}

__global__ void k_fill(const int* __restrict__ edge, const int* __restrict__ rowptr,
                       const int* __restrict__ rank, int* __restrict__ srclist, int E,
                       const int* __restrict__ flags) {
    int i = blockIdx.x * blockDim.x + threadIdx.x;
    if (i >= E) return;
    int is64 = flags[1];
    int s = edge_word(edge, i, is64);
    int d = edge_word(edge, (long long)E + i, is64);
    srclist[rowptr[d] + rank[i]] = s;
}

// ---------------- agg64: Y = Ahat * Xb (64 feats; 8 lanes/node, 8 nodes/wave) ----------------
#define ACC8(v, e) do { \
    acc[0] += bits2f((v).x & 0xFFFFu) * (e); acc[1] += bits2f((v).x >> 16) * (e); \
    acc[2] += bits2f((v).y & 0xFFFFu) * (e); acc[3] += bits2f((v).y >> 16) * (e); \
    acc[4] += bits2f((v).z & 0xFFFFu) * (e); acc[5] += bits2f((v).z >> 16) * (e); \
    acc[6] += bits2f((v).w & 0xFFFFu) * (e); acc[7] += bits2f((v).w >> 16) * (e); } while (0)

__global__ __launch_bounds__(256) void k_agg64(const bf16* __restrict__ h,
                                               const int* __restrict__ srclist,
                                               const int* __restrict__ rowptr,
                                               const int* __restrict__ count,
                                               const float* __restrict__ dinv,
                                               bf16* __restrict__ outb, int N) {
    int wave = threadIdx.x >> 6;
    int lane = threadIdx.x & 63;
    int group = lane >> 3;       // 8 groups of 8 lanes
    int sub = lane & 7;          // 8 lanes x 16B = 128B row
    int i = blockIdx.x * 32 + wave * 8 + group;
    if (i >= N) return;
    int start = rowptr[i];
    int cnt = count[i];
    float di = dinv[i];
    const uint4* hrow = (const uint4*)h;
    float acc[8] = {0.f, 0.f, 0.f, 0.f, 0.f, 0.f, 0.f, 0.f};
    int lb = group << 3;
    for (int jb = 0; jb < cnt; jb += 8) {
        int m = cnt - jb; if (m > 8) m = 8;
        int sv = srclist[start + jb + ((sub < m) ? sub : (m - 1))];
        float dvv = dinv[sv];
        int j = 0;
        for (; j + 4 <= m; j += 4) {
            int s0 = __shfl(sv, lb + j + 0); float e0 = __shfl(dvv, lb + j + 0);
            int s1 = __shfl(sv, lb + j + 1); float e1 = __shfl(dvv, lb + j + 1);
            int s2 = __shfl(sv, lb + j + 2); float e2 = __shfl(dvv, lb + j + 2);
            int s3 = __shfl(sv, lb + j + 3); float e3 = __shfl(dvv, lb + j + 3);
            uint4 v0 = hrow[(size_t)s0 * 8 + sub];
            uint4 v1 = hrow[(size_t)s1 * 8 + sub];
            uint4 v2 = hrow[(size_t)s2 * 8 + sub];
            uint4 v3 = hrow[(size_t)s3 * 8 + sub];
            ACC8(v0, e0); ACC8(v1, e1); ACC8(v2, e2); ACC8(v3, e3);
        }
        for (; j < m; j++) {
            int s0 = __shfl(sv, lb + j); float e0 = __shfl(dvv, lb + j);
            uint4 v0 = hrow[(size_t)s0 * 8 + sub];
            ACC8(v0, e0);
        }
    }
    uint4 vs = hrow[(size_t)i * 8 + sub];
    float self = di * di;
    float o0 = di * acc[0] + bits2f(vs.x & 0xFFFFu) * self;
    float o1 = di * acc[1] + bits2f(vs.x >> 16) * self;
    float o2 = di * acc[2] + bits2f(vs.y & 0xFFFFu) * self;
    float o3 = di * acc[3] + bits2f(vs.y >> 16) * self;
    float o4 = di * acc[4] + bits2f(vs.z & 0xFFFFu) * self;
    float o5 = di * acc[5] + bits2f(vs.z >> 16) * self;
    float o6 = di * acc[6] + bits2f(vs.w & 0xFFFFu) * self;
    float o7 = di * acc[7] + bits2f(vs.w >> 16) * self;
    uint4 pv;
    pv.x = ((unsigned int)f2bits(o1) << 16) | f2bits(o0);
    pv.y = ((unsigned int)f2bits(o3) << 16) | f2bits(o2);
    pv.z = ((unsigned int)f2bits(o5) << 16) | f2bits(o4);
    pv.w = ((unsigned int)f2bits(o7) << 16) | f2bits(o6);
    ((uint4*)outb)[(size_t)i * 8 + sub] = pv;
}

// ---------------- agg128: Z = Ahat * h (128 feats; 16 lanes/node, 4 nodes/wave) ----------------
__global__ __launch_bounds__(256) void k_agg128(const bf16* __restrict__ h,
                                                const int* __restrict__ srclist,
                                                const int* __restrict__ rowptr,
                                                const int* __restrict__ count,
                                                const float* __restrict__ dinv,
                                                bf16* __restrict__ outb, int N) {
    int wave = threadIdx.x >> 6;
    int lane = threadIdx.x & 63;
    int group = lane >> 4;
    int sub = lane & 15;
    int i = blockIdx.x * 16 + wave * 4 + group;
    if (i >= N) return;
    int start = rowptr[i];
    int cnt = count[i];
    float di = dinv[i];
    const uint4* hrow = (const uint4*)h;
    float acc[8] = {0.f, 0.f, 0.f, 0.f, 0.f, 0.f, 0.f, 0.f};
    int lb = group << 4;
    for (int jb = 0; jb < cnt; jb += 16) {
        int m = cnt - jb; if (m > 16) m = 16;
        int sv = srclist[start + jb + ((sub < m) ? sub : (m - 1))];
        float dvv = dinv[sv];
        int j = 0;
        for (; j + 4 <= m; j += 4) {
            int s0 = __shfl(sv, lb + j + 0); float e0 = __shfl(dvv, lb + j + 0);
            int s1 = __shfl(sv, lb + j + 1); float e1 = __shfl(dvv, lb + j + 1);
            int s2 = __shfl(sv, lb + j + 2); float e2 = __shfl(dvv, lb + j + 2);
            int s3 = __shfl(sv, lb + j + 3); float e3 = __shfl(dvv, lb + j + 3);
            uint4 v0 = hrow[(size_t)s0 * 16 + sub];
            uint4 v1 = hrow[(size_t)s1 * 16 + sub];
            uint4 v2 = hrow[(size_t)s2 * 16 + sub];
            uint4 v3 = hrow[(size_t)s3 * 16 + sub];
            ACC8(v0, e0); ACC8(v1, e1); ACC8(v2, e2); ACC8(v3, e3);
        }
        for (; j < m; j++) {
            int s0 = __shfl(sv, lb + j); float e0 = __shfl(dvv, lb + j);
            uint4 v0 = hrow[(size_t)s0 * 16 + sub];
            ACC8(v0, e0);
        }
    }
    uint4 vs = hrow[(size_t)i * 16 + sub];
    float self = di * di;
    float o0 = di * acc[0] + bits2f(vs.x & 0xFFFFu) * self;
    float o1 = di * acc[1] + bits2f(vs.x >> 16) * self;
    float o2 = di * acc[2] + bits2f(vs.y & 0xFFFFu) * self;
    float o3 = di * acc[3] + bits2f(vs.y >> 16) * self;
    float o4 = di * acc[4] + bits2f(vs.z & 0xFFFFu) * self;
    float o5 = di * acc[5] + bits2f(vs.z >> 16) * self;
    float o6 = di * acc[6] + bits2f(vs.w & 0xFFFFu) * self;
    float o7 = di * acc[7] + bits2f(vs.w >> 16) * self;
    uint4 pv;
    pv.x = ((unsigned int)f2bits(o1) << 16) | f2bits(o0);
    pv.y = ((unsigned int)f2bits(o3) << 16) | f2bits(o2);
    pv.z = ((unsigned int)f2bits(o5) << 16) | f2bits(o4);
    pv.w = ((unsigned int)f2bits(o7) << 16) | f2bits(o6);
    ((uint4*)outb)[(size_t)i * 16 + sub] = pv;
}

// ---------------- MFMA GEMM A: h1 = relu(Y @ W1 + b1)  [N,64]->[N,128] ----------------
#define K1PAD 72
__global__ __launch_bounds__(256) void k_gemmA(const bf16* __restrict__ Y,
                                               const bf16* __restrict__ W1t,
                                               const bf16* __restrict__ bias,
                                               bf16* __restrict__ h1, int N) {
    __shared__ bf16 As[64 * K1PAD];
    __shared__ bf16 Wt[HDIM * K1PAD];
    __shared__ float bsf[HDIM];
    int tid = threadIdx.x;
    int base = blockIdx.x * 64;
    {
        const uint4* wsrc = (const uint4*)W1t;
        for (int i = tid; i < HDIM * 8; i += 256) {
            int n = i >> 3, c = i & 7;
            *(uint4*)&Wt[n * K1PAD + c * 8] = wsrc[n * 8 + c];
        }
    }
    {
        const uint4* xb = (const uint4*)Y;
        for (int i = tid; i < 64 * 8; i += 256) {
            int r = i >> 3, c = i & 7;
            int gr = base + r; if (gr >= N) gr = N - 1;
            *(uint4*)&As[r * K1PAD + c * 8] = xb[(size_t)gr * 8 + c];
        }
    }
    if (tid < HDIM) bsf[tid] = b2f(bias[tid]);
    __syncthreads();
    int wid = tid >> 6, lane = tid & 63;
    int l15 = lane & 15, q = lane >> 4;
    int m0 = wid * 16;
    short8 af[2];
#pragma unroll
    for (int kc = 0; kc < 2; kc++)
        af[kc] = *(const short8*)&As[(m0 + l15) * K1PAD + kc * 32 + q * 8];
    f32x4 acc[8];
#pragma unroll
    for (int nt = 0; nt < 8; nt++) {
        acc[nt] = (f32x4){0.f, 0.f, 0.f, 0.f};
#pragma unroll
        for (int kc = 0; kc < 2; kc++) {
            short8 bf = *(const short8*)&Wt[(nt * 16 + l15) * K1PAD + kc * 32 + q * 8];
            acc[nt] = __builtin_amdgcn_mfma_f32_16x16x32_bf16(af[kc], bf, acc[nt], 0, 0, 0);
        }
    }
#pragma unroll
    for (int nt = 0; nt < 8; nt++) {
        int col = nt * 16 + l15;
        float bv = bsf[col];
#pragma unroll
        for (int r = 0; r < 4; r++) {
            int gr = base + m0 + q * 4 + r;
            if (gr < N) h1[(size_t)gr * HDIM + col] = __float2bfloat16(fmaxf(acc[nt][r] + bv, 0.f));
        }
    }
}

// ---------------- MFMA GEMM B: h2 = relu(Z @ W2 + b2)  [N,128]->[N,128] ----------------
#define K2PAD 136
__global__ __launch_bounds__(256) void k_gemmB(const bf16* __restrict__ Z,
                                               const bf16* __restrict__ W2t,
                                               const bf16* __restrict__ bias,
                                               bf16* __restrict__ outp, int N) {
    __shared__ bf16 As[64 * K2PAD];
    __shared__ bf16 Wt[HDIM * K2PAD];
    __shared__ float bsf[HDIM];
    int tid = threadIdx.x;
    int base = blockIdx.x * 64;
    {
        const uint4* wsrc = (const uint4*)W2t;
        for (int i = tid; i < HDIM * 16; i += 256) {
            int n = i >> 4, c = i & 15;
            *(uint4*)&Wt[n * K2PAD + c * 8] = wsrc[n * 16 + c];
        }
    }
    const uint4* xb = (const uint4*)Z;
    for (int i = tid; i < 64 * 16; i += 256) {
        int r = i >> 4, c = i & 15;
        int gr = base + r; if (gr >= N) gr = N - 1;
        *(uint4*)&As[r * K2PAD + c * 8] = xb[(size_t)gr * 16 + c];
    }
    if (tid < HDIM) bsf[tid] = b2f(bias[tid]);
    __syncthreads();
    int wid = tid >> 6, lane = tid & 63;
    int l15 = lane & 15, q = lane >> 4;
    int m0 = wid * 16;
    short8 af[4];
#pragma unroll
    for (int kc = 0; kc < 4; kc++)
        af[kc] = *(const short8*)&As[(m0 + l15) * K2PAD + kc * 32 + q * 8];
    f32x4 acc[8];
#pragma unroll
    for (int nt = 0; nt < 8; nt++) {
        acc[nt] = (f32x4){0.f, 0.f, 0.f, 0.f};
#pragma unroll
        for (int kc = 0; kc < 4; kc++) {
            short8 bf = *(const short8*)&Wt[(nt * 16 + l15) * K2PAD + kc * 32 + q * 8];
            acc[nt] = __builtin_amdgcn_mfma_f32_16x16x32_bf16(af[kc], bf, acc[nt], 0, 0, 0);
        }
    }
#pragma unroll
    for (int nt = 0; nt < 8; nt++) {
        int col = nt * 16 + l15;
        float bv = bsf[col];
#pragma unroll
        for (int r = 0; r < 4; r++) {
            int gr = base + m0 + q * 4 + r;
            if (gr < N) outp[(size_t)gr * HDIM + col] = __float2bfloat16(fmaxf(acc[nt][r] + bv, 0.f));
        }
    }
}

// ---------------- pool phase A: streaming per-graph sums ----------------
__global__ __launch_bounds__(256) void k_pool_sum(const bf16* __restrict__ hact,
                                                  const int* __restrict__ batch,
                                                  float* __restrict__ Gsum,
                                                  float* __restrict__ Gcnt,
                                                  int N, const int* __restrict__ flags) {
    int wave = threadIdx.x >> 6, lane = threadIdx.x & 63;
    int base = blockIdx.x * PROWS;
    int is64 = flags[2];
    const unsigned int* hrow = (const unsigned int*)hact;
    float a0 = 0.f, a1 = 0.f;
    int c = 0, gcur = -1;
    for (int k = 0; k < PROWS / 4; k++) {
        int r = base + wave + 4 * k;
        if (r >= N) break;
        int g = is64 ? batch[2 * r] : batch[r];
        if (g != gcur) {
            if (gcur >= 0) {
                atomicAdd(&Gsum[gcur * HDIM + 2 * lane], a0);
                atomicAdd(&Gsum[gcur * HDIM + 2 * lane + 1], a1);
                if (lane == 0) atomicAdd(&Gcnt[gcur], (float)c);
            }
            a0 = a1 = 0.f; c = 0; gcur = g;
        }
        unsigned int v = hrow[(size_t)r * 64 + lane];
        a0 += bits2f(v & 0xFFFFu);
        a1 += bits2f(v >> 16);
        c++;
    }
    if (gcur >= 0) {
        atomicAdd(&Gsum[gcur * HDIM + 2 * lane], a0);
        atomicAdd(&Gsum[gcur * HDIM + 2 * lane + 1], a1);
        if (lane == 0) atomicAdd(&Gcnt[gcur], (float)c);
    }
}

// ---------------- pool phase B: mean + FC + softmax (wave per graph) ----------------
__global__ __launch_bounds__(256) void k_pool_fc(const float* __restrict__ Gsum,
                                                 const float* __restrict__ Gcnt,
                                                 const bf16* __restrict__ Wfc,
                                                 const bf16* __restrict__ bfc,
                                                 void* __restrict__ out, int G,
                                                 const int* __restrict__ flags) {
    int wave = threadIdx.x >> 6, lane = threadIdx.x & 63;
    int g = blockIdx.x * 4 + wave;
    if (g >= G) return;
    float inv = 1.0f / fmaxf(Gcnt[g], 1.0f);
    float m0 = Gsum[g * HDIM + 2 * lane] * inv;
    float m1 = Gsum[g * HDIM + 2 * lane + 1] * inv;
    float l0 = m0 * b2f(Wfc[(2 * lane) * 2 + 0]) + m1 * b2f(Wfc[(2 * lane + 1) * 2 + 0]);
    float l1 = m0 * b2f(Wfc[(2 * lane) * 2 + 1]) + m1 * b2f(Wfc[(2 * lane + 1) * 2 + 1]);
    for (int s = 32; s; s >>= 1) { l0 += __shfl_down(l0, s); l1 += __shfl_down(l1, s); }
    if (lane == 0) {
        float z0 = l0 + b2f(bfc[0]);
        float z1 = l1 + b2f(bfc[1]);
        float mx = fmaxf(z0, z1);
        float e0 = expf(z0 - mx), e1 = expf(z1 - mx);
        float s = e0 + e1;
        float p0 = e0 / s, p1 = e1 / s;
        if (flags[0]) {
            ((float*)out)[2 * g + 0] = p0;
            ((float*)out)[2 * g + 1] = p1;
        } else {
            ((bf16*)out)[2 * g + 0] = __float2bfloat16(p0);
            ((bf16*)out)[2 * g + 1] = __float2bfloat16(p1);
        }
    }
}

extern "C" void kernel_launch(void* const* d_in, const int* in_sizes, int n_in,
                              void* d_out, int out_size, void* d_ws, size_t ws_size,
                              hipStream_t stream) {
    const void* x    = d_in[0];
    const int*  edge = (const int*)d_in[1];
    const int*  batch= (const int*)d_in[2];
    const void* W1  = d_in[4];
    const void* b1  = d_in[5];
    const void* W2  = d_in[6];
    const void* b2  = d_in[7];
    const void* Wfc = d_in[8];
    const void* bfc = d_in[9];

    int N = in_sizes[0] / FDIM;   // 100000
    int E = in_sizes[1] / 2;      // 1000000
    int G = out_size / 2;         // 512
    int NP = (N + SCHUNK - 1) / SCHUNK;

    // ws layout. count,Gsum,Gcnt contiguous: zeroed by one memset.
    int*   flags  = (int*)d_ws;                          // 64 B
    float* dinv   = (float*)((char*)d_ws + 64);          // N floats
    int*   count  = (int*)(dinv + N);                    // N ints (memset group start)
    float* Gsum   = (float*)(count + N);                 // G*128 floats
    float* Gcnt   = Gsum + (size_t)G * HDIM;             // G floats (memset group end)
    int*   rowptr = (int*)(Gcnt + G);                    // N ints
    int*   parts  = rowptr + N;                          // 256
    int*   partsx = parts + 256;                         // 256
    int*   rank   = partsx + 256;                        // E ints
    int*   srclist= rank + E;                            // E ints
    bf16*  Abuf   = (bf16*)(srclist + E);                // N*128 (Xb in lo half, Y in hi half; later Z)
    bf16*  Bbuf   = Abuf + (size_t)N * HDIM;             // N*128 (h1, later h2)
    bf16*  b1c    = Bbuf + (size_t)N * HDIM;             // 128
    bf16*  b2c    = b1c + HDIM;                          // 128
    bf16*  Wfcc   = b2c + HDIM;                          // 256
    bf16*  bfcc   = Wfcc + 256;                          // 64 (pad)
    bf16*  W1t    = bfcc + 64;                           // 8192
    bf16*  W2t    = W1t + FDIM * HDIM;                   // 16384

    bf16* Xb = Abuf;                       // N*64
    bf16* Y  = Abuf + (size_t)N * FDIM;    // N*64
    bf16* Z  = Abuf;                       // N*128 (Xb,Y dead by then)

    k_prep_flags<<<1, 192, 0, stream>>>((const unsigned short*)W1, edge, batch, flags);
    k_prep_conv<<<32, 256, 0, stream>>>(W1, b1, W2, b2, Wfc, bfc, flags,
                                        W1t, W2t, b1c, b2c, Wfcc, bfcc);
    k_convX<<<(N * 16 + 255) / 256, 256, 0, stream>>>(x, Xb, N * 16, flags);

    hipMemsetAsync(count, 0, ((size_t)N + (size_t)G * HDIM + G) * sizeof(int), stream);
    k_count<<<(E + 255) / 256, 256, 0, stream>>>(edge, count, rank, E, flags);
    k_scan_partial<<<NP, 256, 0, stream>>>(count, parts, N);
    k_scan_parts<<<1, 256, 0, stream>>>(parts, partsx, NP);
    k_scan_final<<<NP, 512, 0, stream>>>(count, partsx, rowptr, dinv, N);
    k_fill<<<(E + 255) / 256, 256, 0, stream>>>(edge, rowptr, rank, srclist, E, flags);

    // layer 1: Y = Ahat*Xb ; h1 = relu(Y W1 + b1)
    k_agg64<<<(N + 31) / 32, 256, 0, stream>>>(Xb, srclist, rowptr, count, dinv, Y, N);
    k_gemmA<<<(N + 63) / 64, 256, 0, stream>>>(Y, W1t, b1c, Bbuf, N);

    // layer 2: Z = Ahat*h1 ; h2 = relu(Z W2 + b2)
    k_agg128<<<(N + 15) / 16, 256, 0, stream>>>(Bbuf, srclist, rowptr, count, dinv, Z, N);
    k_gemmB<<<(N + 63) / 64, 256, 0, stream>>>(Z, W2t, b2c, Bbuf, N);

    // pool + fc + softmax
    k_pool_sum<<<(N + PROWS - 1) / PROWS, 256, 0, stream>>>(Bbuf, batch, Gsum, Gcnt, N, flags);
    k_pool_fc<<<(G + 3) / 4, 256, 0, stream>>>(Gsum, Gcnt, Wfcc, bfcc, d_out, G, flags);
}